// Round 2
// 2241.248 us; speedup vs baseline: 1.4502x; 1.4502x over previous
//
#include <hip/hip_runtime.h>

#define T_DIM 16

typedef __bf16 bf16x8 __attribute__((ext_vector_type(8)));
typedef float  f32x4  __attribute__((ext_vector_type(4)));

// ---------------- conv3d stride(1,2,2) pad 1 (kept for conv1/conv2) ----------------
template<int CI,int HI,int WI,int CO,int HO,int WO,int NCO,bool RELU>
__global__ void conv3d_s122_k(const float* __restrict__ in, const float* __restrict__ wgt,
                              const float* __restrict__ bias, float* __restrict__ out) {
  const int tx = threadIdx.x;
  const int w0 = tx * 4;
  const int h  = blockIdx.x * blockDim.y + threadIdx.y;
  const int co0 = blockIdx.y * NCO;
  const int bz = blockIdx.z;
  const int b = bz >> 4, t = bz & 15;

  float acc[NCO][4];
  #pragma unroll
  for (int i = 0; i < NCO; ++i) {
    const float bv = bias[co0 + i];
    #pragma unroll
    for (int j = 0; j < 4; ++j) acc[i][j] = bv;
  }
  const int cs = 2 * w0 - 2;

  for (int ci = 0; ci < CI; ++ci) {
    const float* inc = in + (size_t)((b * CI + ci) * T_DIM) * (HI * WI);
    const float* wc  = wgt + ((size_t)co0 * CI + ci) * 27;
    #pragma unroll
    for (int kd = 0; kd < 3; ++kd) {
      const int t2 = t - 1 + kd;
      if (t2 < 0 || t2 >= T_DIM) continue;
      const float* ip = inc + t2 * (HI * WI);
      #pragma unroll
      for (int kh = 0; kh < 3; ++kh) {
        const int hh = 2 * h - 1 + kh;
        float v[10];
        if (hh >= 0) {
          const float* r = ip + hh * WI + cs;
          if (cs >= 0) { float2 u = *(const float2*)r; v[0] = u.x; v[1] = u.y; }
          else         { v[0] = 0.f; v[1] = 0.f; }
          float2 u1 = *(const float2*)(r + 2); v[2] = u1.x; v[3] = u1.y;
          float2 u2 = *(const float2*)(r + 4); v[4] = u2.x; v[5] = u2.y;
          float2 u3 = *(const float2*)(r + 6); v[6] = u3.x; v[7] = u3.y;
          float2 u4 = *(const float2*)(r + 8); v[8] = u4.x; v[9] = u4.y;
        } else {
          #pragma unroll
          for (int z = 0; z < 10; ++z) v[z] = 0.f;
        }
        #pragma unroll
        for (int i = 0; i < NCO; ++i) {
          const float* wp = wc + (size_t)i * (CI * 27) + kd * 9 + kh * 3;
          const float wa = wp[0], wb = wp[1], wcc = wp[2];
          #pragma unroll
          for (int wi = 0; wi < 4; ++wi) {
            acc[i][wi] = fmaf(v[1 + 2*wi], wa,  acc[i][wi]);
            acc[i][wi] = fmaf(v[2 + 2*wi], wb,  acc[i][wi]);
            acc[i][wi] = fmaf(v[3 + 2*wi], wcc, acc[i][wi]);
          }
        }
      }
    }
  }
  #pragma unroll
  for (int i = 0; i < NCO; ++i) {
    float4 o;
    float* po = (float*)&o;
    #pragma unroll
    for (int j = 0; j < 4; ++j) {
      float x = acc[i][j];
      if (RELU) x = fmaxf(x, 0.f);
      po[j] = x;
    }
    *(float4*)(out + ((size_t)(((b * CO + co0 + i) * T_DIM + t) * HO + h)) * WO + w0) = o;
  }
}

// ---------------- bf16x2 split helper: pack(hi | lo<<16) ----------------
__device__ __forceinline__ unsigned int splitpack(float x) {
  unsigned int u = __float_as_uint(x);
  unsigned int hi = (u + 0x7fffu + ((u >> 16) & 1u)) >> 16;
  float l = x - __uint_as_float(hi << 16);
  unsigned int ul = __float_as_uint(l);
  unsigned int lo = (ul + 0x7fffu + ((ul >> 16) & 1u)) >> 16;
  return hi | (lo << 16);
}

// ---------------- h2 -> parity-decomposed padded bf16x2 planes ----------------
// h2p[b][ci][t][pl(=ph*2+pw)][r 17][c 17], u32 = (hi | lo<<16)
// P[ph][pw][r][c] = h2[2(r-1)+ph][2(c-1)+pw], zero when r==0 || c==0.
// total: 8192 slots * 4*289 = 9,469,952 u32
__global__ void split_h2_k(const float* __restrict__ h2, unsigned int* __restrict__ h2p) {
  unsigned int o = blockIdx.x * 256u + threadIdx.x;      // grid exact: 36992*256
  unsigned int within = o % 1156u, slot = o / 1156u;     // slot = (b*256+ci)*16 + t
  unsigned int pl = within / 289u, rc = within % 289u;
  unsigned int r = rc / 17u, c = rc % 17u;
  unsigned int ph = pl >> 1, pw = pl & 1;
  float x = 0.f;
  if (r >= 1u && c >= 1u) {
    unsigned int hh = 2u*r - 2u + ph, ww = 2u*c - 2u + pw;
    x = h2[(size_t)slot * 1024u + hh * 32u + ww];
  }
  h2p[o] = splitpack(x);
}

// ---------------- w3 -> MFMA-tile layout, separate hi/lo bf16 arrays ----------------
// out[tap 27][cic 8][cb 4][kg 4][col 128][j 8] = w3[co=cb*128+col][ci=cic*32+kg*8+j][tap]
__global__ void split_w3_k(const float* __restrict__ w3, unsigned short* __restrict__ whi,
                           unsigned short* __restrict__ wlo) {
  unsigned int o = blockIdx.x * 256u + threadIdx.x;      // grid exact: 13824*256 = 27<<17
  unsigned int j   = o & 7u;
  unsigned int col = (o >> 3) & 127u;
  unsigned int kg  = (o >> 10) & 3u;
  unsigned int cb  = (o >> 12) & 3u;
  unsigned int cic = (o >> 14) & 7u;
  unsigned int tap = o >> 17;
  unsigned int co = cb * 128u + col, ci = cic * 32u + kg * 8u + j;
  float x = w3[((size_t)co * 256u + ci) * 27u + tap];
  unsigned int p = splitpack(x);
  whi[o] = (unsigned short)(p & 0xffffu);
  wlo[o] = (unsigned short)(p >> 16);
}

// ---------------- conv3 as implicit-GEMM MFMA (bf16x2, 3 products) ----------------
#define NCH 216   // 27 taps * 8 ci-chunks of 32

__device__ __forceinline__ void mfma_bf16(f32x4& d, uint4 a, uint4 b) {
  d = __builtin_amdgcn_mfma_f32_16x16x32_bf16(
        __builtin_bit_cast(bf16x8, a), __builtin_bit_cast(bf16x8, b), d, 0, 0, 0);
}

__global__ __launch_bounds__(512) void conv3_mfma_k(
    const unsigned int* __restrict__ xp,    // h2p planes (packed hi|lo)
    const unsigned short* __restrict__ whi, // w3 hi tiles
    const unsigned short* __restrict__ wlo, // w3 lo tiles
    const float* __restrict__ bias,
    float* __restrict__ f) {                // [2][512][16][16][16]
  // LDS (ushort units): Ahi [0,4096) Alo [4096,8192) Bhi [8192,12288) Blo [12288,16384)
  __shared__ __align__(16) unsigned short lds[16384];

  const int tid  = threadIdx.x;
  const int lane = tid & 63;
  const int wid  = tid >> 6;           // 8 waves: 2(M) x 4(N)
  const int wm   = wid >> 2, wn = wid & 3;
  const int cb = blockIdx.x;           // co block (128)
  const int hb = blockIdx.y;           // h half (8 rows)
  const int bt = blockIdx.z;           // b*16 + t
  const int b = bt >> 4, t = bt & 15;

  // ---- stager mapping: kg = tid>>7, n = tid&127 ----
  const int skg = tid >> 7;
  const int sn  = tid & 127;
  const int shn = hb * 8 + (sn >> 4);
  const int swn = sn & 15;
  const int sbase = b * 4734976 + skg * 147968 + shn * 17 + swn; // b*(256*16*1156) + (skg*8)*18496 + r0*17 + c0

  // ---- loop-invariant LDS pointers ----
  const int lc = lane & 15, kgl = lane >> 4;
  const uint4* pAhi[4]; const uint4* pAlo[4];
  #pragma unroll
  for (int mf = 0; mf < 4; ++mf) {
    const int off = kgl * 1024 + (wm * 64 + mf * 16 + lc) * 8;
    pAhi[mf] = (const uint4*)&lds[off];
    pAlo[mf] = (const uint4*)&lds[4096 + off];
  }
  const uint4* pBhi[2]; const uint4* pBlo[2];
  #pragma unroll
  for (int nf = 0; nf < 2; ++nf) {
    const int off = kgl * 1024 + (wn * 32 + nf * 16 + lc) * 8;
    pBhi[nf] = (const uint4*)&lds[8192 + off];
    pBlo[nf] = (const uint4*)&lds[12288 + off];
  }
  uint4* wAhi = (uint4*)&lds[tid * 8];
  uint4* wAlo = (uint4*)&lds[4096 + tid * 8];
  uint4* wBhi = (uint4*)&lds[8192  + (skg * 128 + sn) * 8];
  uint4* wBlo = (uint4*)&lds[12288 + (skg * 128 + sn) * 8];

  f32x4 acc[4][2];
  #pragma unroll
  for (int mf = 0; mf < 4; ++mf)
    #pragma unroll
    for (int nf = 0; nf < 2; ++nf) acc[mf][nf] = (f32x4)(0.f);

  uint4 avh, avl;
  unsigned int vals[8];

  auto issue = [&](int ic) {
    const int tap = ic >> 3, cic = ic & 7;
    const int kd = tap / 9, r9 = tap % 9;
    const int kh = r9 / 3, kw = r9 % 3;
    const int tt = t + kd - 1;
    const bool oob = (tt < 0) || (tt > 15);
    const int pl   = ((kh != 1) ? 2 : 0) + ((kw != 1) ? 1 : 0);
    const int rofs = (kh != 0) ? 1 : 0;
    const int cofs = (kw != 0) ? 1 : 0;
    const int idx0 = sbase + cic * 591872 + tt * 1156 + pl * 289 + rofs * 17 + cofs;
    #pragma unroll
    for (int j = 0; j < 8; ++j) {
      unsigned int sidx = oob ? 0u : (unsigned int)(idx0 + j * 18496);
      unsigned int v = xp[sidx];
      vals[j] = oob ? 0u : v;
    }
    const size_t slab = ((size_t)((tap * 8 + cic) * 4 + cb)) << 12;
    avh = *(const uint4*)(whi + slab + tid * 8);
    avl = *(const uint4*)(wlo + slab + tid * 8);
  };

  issue(0);

  for (int ic = 0; ic < NCH; ++ic) {
    __syncthreads();                     // prev MFMA reads done; prefetch ready
    *wAhi = avh;
    *wAlo = avl;
    uint4 H, L;
    H.x = (vals[0] & 0xffffu) | (vals[1] << 16);  L.x = (vals[0] >> 16) | (vals[1] & 0xffff0000u);
    H.y = (vals[2] & 0xffffu) | (vals[3] << 16);  L.y = (vals[2] >> 16) | (vals[3] & 0xffff0000u);
    H.z = (vals[4] & 0xffffu) | (vals[5] << 16);  L.z = (vals[4] >> 16) | (vals[5] & 0xffff0000u);
    H.w = (vals[6] & 0xffffu) | (vals[7] << 16);  L.w = (vals[6] >> 16) | (vals[7] & 0xffff0000u);
    *wBhi = H;
    *wBlo = L;
    __syncthreads();                     // tile visible
    if (ic + 1 < NCH) issue(ic + 1);     // overlap next-chunk global loads with MFMA

    uint4 ah[4], al[4], bh[2], bl[2];
    #pragma unroll
    for (int mf = 0; mf < 4; ++mf) { ah[mf] = *pAhi[mf]; al[mf] = *pAlo[mf]; }
    #pragma unroll
    for (int nf = 0; nf < 2; ++nf) { bh[nf] = *pBhi[nf]; bl[nf] = *pBlo[nf]; }

    #pragma unroll
    for (int mf = 0; mf < 4; ++mf)
      #pragma unroll
      for (int nf = 0; nf < 2; ++nf) mfma_bf16(acc[mf][nf], ah[mf], bh[nf]);
    #pragma unroll
    for (int mf = 0; mf < 4; ++mf)
      #pragma unroll
      for (int nf = 0; nf < 2; ++nf) mfma_bf16(acc[mf][nf], ah[mf], bl[nf]);
    #pragma unroll
    for (int mf = 0; mf < 4; ++mf)
      #pragma unroll
      for (int nf = 0; nf < 2; ++nf) mfma_bf16(acc[mf][nf], al[mf], bh[nf]);
  }

  const int lr4 = (lane >> 4) * 4;
  #pragma unroll
  for (int mf = 0; mf < 4; ++mf) {
    #pragma unroll
    for (int nf = 0; nf < 2; ++nf) {
      const int n_l = wn * 32 + nf * 16 + lc;
      const int hh2 = hb * 8 + (n_l >> 4);
      const int ww2 = n_l & 15;
      #pragma unroll
      for (int r = 0; r < 4; ++r) {
        const int co_g = cb * 128 + wm * 64 + mf * 16 + lr4 + r;
        f[((size_t)((b * 512 + co_g) * 16 + t)) * 256 + hh2 * 16 + ww2] = acc[mf][nf][r] + bias[co_g];
      }
    }
  }
}

// ---------------- codebook transpose: cbt[c][v] = cb[v][c] ----------------
__global__ void transpose_cb_k(const float* __restrict__ cb, float* __restrict__ cbt) {
  __shared__ float tile[32][33];
  const int v0 = blockIdx.x * 32, c0 = blockIdx.y * 32;
  const int tx = threadIdx.x, ty = threadIdx.y;   // (32,8)
  #pragma unroll
  for (int r = 0; r < 32; r += 8)
    tile[ty + r][tx] = cb[(size_t)(v0 + ty + r) * 512 + c0 + tx];
  __syncthreads();
  #pragma unroll
  for (int r = 0; r < 32; r += 8)
    cbt[(size_t)(c0 + ty + r) * 8192 + v0 + tx] = tile[tx][ty + r];
}

// ---------------- codebook squared norms ----------------
__global__ void c2_k(const float* __restrict__ cb, float* __restrict__ c2) {
  const int wid = threadIdx.x >> 6, lane = threadIdx.x & 63;
  const int v = blockIdx.x * 4 + wid;
  const float* row = cb + (size_t)v * 512 + lane * 8;
  float4 a = *(const float4*)row, b = *(const float4*)(row + 4);
  float s = a.x*a.x + a.y*a.y + a.z*a.z + a.w*a.w
          + b.x*b.x + b.y*b.y + b.z*b.z + b.w*b.w;
  #pragma unroll
  for (int off = 32; off; off >>= 1) s += __shfl_down(s, off);
  if (lane == 0) c2[v] = s;
}

// ---------------- VQ: fused GEMM (dist = c2 - 2*dot) + argmin ----------------
#define VQ_KC 16
__global__ void vq_k(const float* __restrict__ f,    // [B][512][4096]
                     const float* __restrict__ cbt,  // [512][8192]
                     const float* __restrict__ c2,
                     float* __restrict__ pval, int* __restrict__ pidx) {
  __shared__ float A[VQ_KC][68];
  __shared__ float Bs[VQ_KC][132];
  const int tid = threadIdx.x;       // 0..127
  const int tx = tid & 15, ty = tid >> 4;
  const int sc = blockIdx.x;         // 0..15 superchunk of 512 v
  const int tb = blockIdx.y;         // 0..127 token block (64 tokens)
  const int b = tb >> 6;
  const int n0 = (tb & 63) * 64;
  const float* fb = f + (size_t)b * 512 * 4096;

  const int skk = tid >> 3;          // 0..15
  const int sA = (tid & 7) * 8;
  const int sB = (tid & 7) * 16;

  float best[8]; int bidx[8];
  #pragma unroll
  for (int i = 0; i < 8; ++i) { best[i] = 3.4e38f; bidx[i] = 0; }

  for (int vt = 0; vt < 4; ++vt) {
    const int v0 = sc * 512 + vt * 128;
    float acc[8][8];
    #pragma unroll
    for (int i = 0; i < 8; ++i)
      #pragma unroll
      for (int j = 0; j < 8; ++j) acc[i][j] = 0.f;

    for (int k0 = 0; k0 < 512; k0 += VQ_KC) {
      __syncthreads();
      {
        const float* src = fb + (size_t)(k0 + skk) * 4096 + n0 + sA;
        *(float4*)&A[skk][sA]     = *(const float4*)src;
        *(float4*)&A[skk][sA + 4] = *(const float4*)(src + 4);
      }
      {
        const float* src = cbt + (size_t)(k0 + skk) * 8192 + v0 + sB;
        *(float4*)&Bs[skk][sB]      = *(const float4*)src;
        *(float4*)&Bs[skk][sB + 4]  = *(const float4*)(src + 4);
        *(float4*)&Bs[skk][sB + 8]  = *(const float4*)(src + 8);
        *(float4*)&Bs[skk][sB + 12] = *(const float4*)(src + 12);
      }
      __syncthreads();
      #pragma unroll
      for (int kk = 0; kk < VQ_KC; ++kk) {
        float a[8], bv[8];
        *(float4*)&a[0]  = *(float4*)&A[kk][ty * 8];
        *(float4*)&a[4]  = *(float4*)&A[kk][ty * 8 + 4];
        *(float4*)&bv[0] = *(float4*)&Bs[kk][tx * 4];
        *(float4*)&bv[4] = *(float4*)&Bs[kk][64 + tx * 4];
        #pragma unroll
        for (int i = 0; i < 8; ++i)
          #pragma unroll
          for (int j = 0; j < 8; ++j)
            acc[i][j] = fmaf(a[i], bv[j], acc[i][j]);
      }
    }
    float cc[8];
    *(float4*)&cc[0] = *(const float4*)(c2 + v0 + tx * 4);
    *(float4*)&cc[4] = *(const float4*)(c2 + v0 + 64 + tx * 4);
    #pragma unroll
    for (int j = 0; j < 8; ++j) {
      const int vg = v0 + ((j < 4) ? (tx * 4 + j) : (64 + tx * 4 + (j - 4)));
      #pragma unroll
      for (int i = 0; i < 8; ++i) {
        const float d = cc[j] - 2.f * acc[i][j];
        if (d < best[i] || (d == best[i] && vg < bidx[i])) { best[i] = d; bidx[i] = vg; }
      }
    }
  }
  #pragma unroll
  for (int off = 1; off < 16; off <<= 1) {
    #pragma unroll
    for (int i = 0; i < 8; ++i) {
      const float ov = __shfl_xor(best[i], off);
      const int   oi = __shfl_xor(bidx[i], off);
      if (ov < best[i] || (ov == best[i] && oi < bidx[i])) { best[i] = ov; bidx[i] = oi; }
    }
  }
  if (tx == 0) {
    #pragma unroll
    for (int i = 0; i < 8; ++i) {
      const int tok = tb * 64 + ty * 8 + i;
      pval[(size_t)tok * 16 + sc] = best[i];
      pidx[(size_t)tok * 16 + sc] = bidx[i];
    }
  }
}

__global__ void vq_reduce_k(const float* __restrict__ pval, const int* __restrict__ pidx,
                            int* __restrict__ tokens, float* __restrict__ out_tok) {
  const int tok = blockIdx.x * blockDim.x + threadIdx.x;  // 8192
  float best = 3.4e38f; int bi = 0;
  for (int s = 0; s < 16; ++s) {
    const float v = pval[(size_t)tok * 16 + s];
    const int idx = pidx[(size_t)tok * 16 + s];
    if (v < best || (v == best && idx < bi)) { best = v; bi = idx; }
  }
  tokens[tok] = bi;
  out_tok[tok] = (float)bi;
}

__global__ void gather_k(const int* __restrict__ tokens, const float* __restrict__ emb,
                         float* __restrict__ out) {
  const int i = blockIdx.x * blockDim.x + threadIdx.x;  // 1,048,576 float4s
  const int n = i >> 7;
  const int c4 = (i & 127) * 4;
  const int tk = tokens[n];
  float4 v = *(const float4*)(emb + (size_t)tk * 512 + c4);
  *(float4*)(out + (size_t)n * 512 + c4) = v;
}

extern "C" void kernel_launch(void* const* d_in, const int* in_sizes, int n_in,
                              void* d_out, int out_size, void* d_ws, size_t ws_size,
                              hipStream_t stream) {
  const float* video = (const float*)d_in[0];
  const float* w1 = (const float*)d_in[1];
  const float* b1 = (const float*)d_in[2];
  const float* w2 = (const float*)d_in[3];
  const float* b2 = (const float*)d_in[4];
  const float* w3 = (const float*)d_in[5];
  const float* b3 = (const float*)d_in[6];
  const float* cb  = (const float*)d_in[7];
  const float* emb = (const float*)d_in[8];

  // ---- workspace layout (floats) ----
  // region A [0 .. 16,777,216): h1 (conv1 out / conv2 in); dead after conv2, reused:
  //    h2p  u32 [0 .. 9,469,952)        parity/pad/bf16x2 planes of h2
  //    f        [9,469,952 .. 13,664,256)
  //    c2       [13,664,256 .. 13,672,448)
  // region B [16,777,216 .. 25,165,824): h2; dead after split_h2, reused:
  //    cbt      [16,777,216 .. 20,971,520)
  // region C [25,165,824 ..): pval / pidx / tokens (unchanged)
  // d_out is scratch for split-w3 tiles until vq_reduce/gather overwrite it.
  float* ws = (float*)d_ws;
  float* h1   = ws;
  unsigned int* h2p = (unsigned int*)ws;
  float* f    = ws + 9469952;
  float* c2v  = ws + 13664256;
  float* h2   = ws + 16777216;
  float* cbt  = ws + 16777216;
  float* pval = ws + 25165824;            //   131,072
  int*   pidx = (int*)(pval + 131072);    //   131,072
  int*   tokens = pidx + 131072;          //     8,192
  unsigned short* whi = (unsigned short*)d_out;   // 3,538,944 ushorts
  unsigned short* wlo = whi + 3538944;            // 3,538,944 ushorts
  float* out_tok = (float*)d_out;
  float* out_emb = (float*)d_out + 8192;

  hipLaunchKernelGGL((conv3d_s122_k<3, 128, 128, 128, 64, 64, 8, true>),
                     dim3(4, 16, 32), dim3(16, 16), 0, stream, video, w1, b1, h1);
  hipLaunchKernelGGL((conv3d_s122_k<128, 64, 64, 256, 32, 32, 8, true>),
                     dim3(1, 32, 32), dim3(8, 32), 0, stream, h1, w2, b2, h2);
  // h1 dead; build bf16x2 parity planes of h2 into region A
  hipLaunchKernelGGL(split_h2_k, dim3(36992), dim3(256), 0, stream, h2, h2p);
  // w3 -> MFMA tiles (into d_out scratch)
  hipLaunchKernelGGL(split_w3_k, dim3(13824), dim3(256), 0, stream, w3, whi, wlo);
  // h2 dead from here; cbt reuses its space
  hipLaunchKernelGGL(transpose_cb_k, dim3(256, 16), dim3(32, 8), 0, stream, cb, cbt);
  hipLaunchKernelGGL(c2_k, dim3(2048), dim3(256), 0, stream, cb, c2v);
  // conv3 on matrix cores
  hipLaunchKernelGGL(conv3_mfma_k, dim3(4, 2, 32), dim3(512), 0, stream,
                     h2p, whi, wlo, b3, f);
  hipLaunchKernelGGL(vq_k, dim3(16, 128), dim3(128), 0, stream, f, cbt, c2v, pval, pidx);
  hipLaunchKernelGGL(vq_reduce_k, dim3(32), dim3(256), 0, stream, pval, pidx, tokens, out_tok);
  hipLaunchKernelGGL(gather_k, dim3(4096), dim3(256), 0, stream, tokens, emb, out_emb);
}

// Round 3
// 1448.897 us; speedup vs baseline: 2.2433x; 1.5469x over previous
//
#include <hip/hip_runtime.h>

#define T_DIM 16

typedef __bf16 bf16x8 __attribute__((ext_vector_type(8)));
typedef float  f32x4  __attribute__((ext_vector_type(4)));

// ---------------- conv3d stride(1,2,2) pad 1 (kept for conv1/conv2) ----------------
template<int CI,int HI,int WI,int CO,int HO,int WO,int NCO,bool RELU>
__global__ void conv3d_s122_k(const float* __restrict__ in, const float* __restrict__ wgt,
                              const float* __restrict__ bias, float* __restrict__ out) {
  const int tx = threadIdx.x;
  const int w0 = tx * 4;
  const int h  = blockIdx.x * blockDim.y + threadIdx.y;
  const int co0 = blockIdx.y * NCO;
  const int bz = blockIdx.z;
  const int b = bz >> 4, t = bz & 15;

  float acc[NCO][4];
  #pragma unroll
  for (int i = 0; i < NCO; ++i) {
    const float bv = bias[co0 + i];
    #pragma unroll
    for (int j = 0; j < 4; ++j) acc[i][j] = bv;
  }
  const int cs = 2 * w0 - 2;

  for (int ci = 0; ci < CI; ++ci) {
    const float* inc = in + (size_t)((b * CI + ci) * T_DIM) * (HI * WI);
    const float* wc  = wgt + ((size_t)co0 * CI + ci) * 27;
    #pragma unroll
    for (int kd = 0; kd < 3; ++kd) {
      const int t2 = t - 1 + kd;
      if (t2 < 0 || t2 >= T_DIM) continue;
      const float* ip = inc + t2 * (HI * WI);
      #pragma unroll
      for (int kh = 0; kh < 3; ++kh) {
        const int hh = 2 * h - 1 + kh;
        float v[10];
        if (hh >= 0) {
          const float* r = ip + hh * WI + cs;
          if (cs >= 0) { float2 u = *(const float2*)r; v[0] = u.x; v[1] = u.y; }
          else         { v[0] = 0.f; v[1] = 0.f; }
          float2 u1 = *(const float2*)(r + 2); v[2] = u1.x; v[3] = u1.y;
          float2 u2 = *(const float2*)(r + 4); v[4] = u2.x; v[5] = u2.y;
          float2 u3 = *(const float2*)(r + 6); v[6] = u3.x; v[7] = u3.y;
          float2 u4 = *(const float2*)(r + 8); v[8] = u4.x; v[9] = u4.y;
        } else {
          #pragma unroll
          for (int z = 0; z < 10; ++z) v[z] = 0.f;
        }
        #pragma unroll
        for (int i = 0; i < NCO; ++i) {
          const float* wp = wc + (size_t)i * (CI * 27) + kd * 9 + kh * 3;
          const float wa = wp[0], wb = wp[1], wcc = wp[2];
          #pragma unroll
          for (int wi = 0; wi < 4; ++wi) {
            acc[i][wi] = fmaf(v[1 + 2*wi], wa,  acc[i][wi]);
            acc[i][wi] = fmaf(v[2 + 2*wi], wb,  acc[i][wi]);
            acc[i][wi] = fmaf(v[3 + 2*wi], wcc, acc[i][wi]);
          }
        }
      }
    }
  }
  #pragma unroll
  for (int i = 0; i < NCO; ++i) {
    float4 o;
    float* po = (float*)&o;
    #pragma unroll
    for (int j = 0; j < 4; ++j) {
      float x = acc[i][j];
      if (RELU) x = fmaxf(x, 0.f);
      po[j] = x;
    }
    *(float4*)(out + ((size_t)(((b * CO + co0 + i) * T_DIM + t) * HO + h)) * WO + w0) = o;
  }
}

// ---------------- bf16x2 split helper: pack(hi | lo<<16) ----------------
__device__ __forceinline__ unsigned int splitpack(float x) {
  unsigned int u = __float_as_uint(x);
  unsigned int hi = (u + 0x7fffu + ((u >> 16) & 1u)) >> 16;
  float l = x - __uint_as_float(hi << 16);
  unsigned int ul = __float_as_uint(l);
  unsigned int lo = (ul + 0x7fffu + ((ul >> 16) & 1u)) >> 16;
  return hi | (lo << 16);
}

// ---------------- h2 -> parity-decomposed padded bf16x2 planes ----------------
__global__ void split_h2_k(const float* __restrict__ h2, unsigned int* __restrict__ h2p) {
  unsigned int o = blockIdx.x * 256u + threadIdx.x;      // grid exact: 36992*256
  unsigned int within = o % 1156u, slot = o / 1156u;     // slot = (b*256+ci)*16 + t
  unsigned int pl = within / 289u, rc = within % 289u;
  unsigned int r = rc / 17u, c = rc % 17u;
  unsigned int ph = pl >> 1, pw = pl & 1;
  float x = 0.f;
  if (r >= 1u && c >= 1u) {
    unsigned int hh = 2u*r - 2u + ph, ww = 2u*c - 2u + pw;
    x = h2[(size_t)slot * 1024u + hh * 32u + ww];
  }
  h2p[o] = splitpack(x);
}

// ---------------- w3 -> MFMA-tile layout, separate hi/lo bf16 arrays ----------------
__global__ void split_w3_k(const float* __restrict__ w3, unsigned short* __restrict__ whi,
                           unsigned short* __restrict__ wlo) {
  unsigned int o = blockIdx.x * 256u + threadIdx.x;      // grid exact: 13824*256 = 27<<17
  unsigned int j   = o & 7u;
  unsigned int col = (o >> 3) & 127u;
  unsigned int kg  = (o >> 10) & 3u;
  unsigned int cb  = (o >> 12) & 3u;
  unsigned int cic = (o >> 14) & 7u;
  unsigned int tap = o >> 17;
  unsigned int co = cb * 128u + col, ci = cic * 32u + kg * 8u + j;
  float x = w3[((size_t)co * 256u + ci) * 27u + tap];
  unsigned int p = splitpack(x);
  whi[o] = (unsigned short)(p & 0xffffu);
  wlo[o] = (unsigned short)(p >> 16);
}

// ---------------- codebook -> tiled hi/lo: idx = (vb*16+kc)*4096 + kq*1024 + row*8 + j ----
__global__ void split_cb_k(const float* __restrict__ cb, unsigned short* __restrict__ cbhi,
                           unsigned short* __restrict__ cblo) {
  unsigned int o = blockIdx.x * 256u + threadIdx.x;      // grid exact: 16384*256 = 2^22
  unsigned int j   = o & 7u;
  unsigned int row = (o >> 3) & 127u;
  unsigned int kq  = (o >> 10) & 3u;
  unsigned int kc  = (o >> 12) & 15u;
  unsigned int vb  = o >> 16;
  unsigned int v = vb * 128u + row, k = kc * 32u + kq * 8u + j;
  float x = cb[(size_t)v * 512u + k];
  unsigned int p = splitpack(x);
  cbhi[o] = (unsigned short)(p & 0xffffu);
  cblo[o] = (unsigned short)(p >> 16);
}

// ---------------- codebook squared norms ----------------
__global__ void c2_k(const float* __restrict__ cb, float* __restrict__ c2) {
  const int wid = threadIdx.x >> 6, lane = threadIdx.x & 63;
  const int v = blockIdx.x * 4 + wid;
  const float* row = cb + (size_t)v * 512 + lane * 8;
  float4 a = *(const float4*)row, b = *(const float4*)(row + 4);
  float s = a.x*a.x + a.y*a.y + a.z*a.z + a.w*a.w
          + b.x*b.x + b.y*b.y + b.z*b.z + b.w*b.w;
  #pragma unroll
  for (int off = 32; off; off >>= 1) s += __shfl_down(s, off);
  if (lane == 0) c2[v] = s;
}

// ---------------- conv3 as implicit-GEMM MFMA (bf16x2, 3 products) ----------------
#define NCH 216   // 27 taps * 8 ci-chunks of 32

__device__ __forceinline__ void mfma_bf16(f32x4& d, uint4 a, uint4 b) {
  d = __builtin_amdgcn_mfma_f32_16x16x32_bf16(
        __builtin_bit_cast(bf16x8, a), __builtin_bit_cast(bf16x8, b), d, 0, 0, 0);
}

__global__ __launch_bounds__(512) void conv3_mfma_k(
    const unsigned int* __restrict__ xp,    // h2p planes (packed hi|lo)
    const unsigned short* __restrict__ whi, // w3 hi tiles
    const unsigned short* __restrict__ wlo, // w3 lo tiles
    const float* __restrict__ bias,
    unsigned short* __restrict__ fhi,       // tiled features hi
    unsigned short* __restrict__ flo) {     // tiled features lo
  __shared__ __align__(16) unsigned short lds[16384];

  const int tid  = threadIdx.x;
  const int lane = tid & 63;
  const int wid  = tid >> 6;           // 8 waves: 2(M) x 4(N)
  const int wm   = wid >> 2, wn = wid & 3;
  const int cb = blockIdx.x;           // co block (128)
  const int hb = blockIdx.y;           // h half (8 rows)
  const int bt = blockIdx.z;           // b*16 + t
  const int b = bt >> 4, t = bt & 15;

  const int skg = tid >> 7;
  const int sn  = tid & 127;
  const int shn = hb * 8 + (sn >> 4);
  const int swn = sn & 15;
  const int sbase = b * 4734976 + skg * 147968 + shn * 17 + swn;

  const int lc = lane & 15, kgl = lane >> 4;
  const uint4* pAhi[4]; const uint4* pAlo[4];
  #pragma unroll
  for (int mf = 0; mf < 4; ++mf) {
    const int off = kgl * 1024 + (wm * 64 + mf * 16 + lc) * 8;
    pAhi[mf] = (const uint4*)&lds[off];
    pAlo[mf] = (const uint4*)&lds[4096 + off];
  }
  const uint4* pBhi[2]; const uint4* pBlo[2];
  #pragma unroll
  for (int nf = 0; nf < 2; ++nf) {
    const int off = kgl * 1024 + (wn * 32 + nf * 16 + lc) * 8;
    pBhi[nf] = (const uint4*)&lds[8192 + off];
    pBlo[nf] = (const uint4*)&lds[12288 + off];
  }
  uint4* wAhi = (uint4*)&lds[tid * 8];
  uint4* wAlo = (uint4*)&lds[4096 + tid * 8];
  uint4* wBhi = (uint4*)&lds[8192  + (skg * 128 + sn) * 8];
  uint4* wBlo = (uint4*)&lds[12288 + (skg * 128 + sn) * 8];

  f32x4 acc[4][2];
  #pragma unroll
  for (int mf = 0; mf < 4; ++mf)
    #pragma unroll
    for (int nf = 0; nf < 2; ++nf) acc[mf][nf] = (f32x4)(0.f);

  uint4 avh, avl;
  unsigned int vals[8];

  auto issue = [&](int ic) {
    const int tap = ic >> 3, cic = ic & 7;
    const int kd = tap / 9, r9 = tap % 9;
    const int kh = r9 / 3, kw = r9 % 3;
    const int tt = t + kd - 1;
    const bool oob = (tt < 0) || (tt > 15);
    const int pl   = ((kh != 1) ? 2 : 0) + ((kw != 1) ? 1 : 0);
    const int rofs = (kh != 0) ? 1 : 0;
    const int cofs = (kw != 0) ? 1 : 0;
    const int idx0 = sbase + cic * 591872 + tt * 1156 + pl * 289 + rofs * 17 + cofs;
    #pragma unroll
    for (int j = 0; j < 8; ++j) {
      unsigned int sidx = oob ? 0u : (unsigned int)(idx0 + j * 18496);
      unsigned int v = xp[sidx];
      vals[j] = oob ? 0u : v;
    }
    const size_t slab = ((size_t)((tap * 8 + cic) * 4 + cb)) << 12;
    avh = *(const uint4*)(whi + slab + tid * 8);
    avl = *(const uint4*)(wlo + slab + tid * 8);
  };

  issue(0);

  for (int ic = 0; ic < NCH; ++ic) {
    __syncthreads();
    *wAhi = avh;
    *wAlo = avl;
    uint4 H, L;
    H.x = (vals[0] & 0xffffu) | (vals[1] << 16);  L.x = (vals[0] >> 16) | (vals[1] & 0xffff0000u);
    H.y = (vals[2] & 0xffffu) | (vals[3] << 16);  L.y = (vals[2] >> 16) | (vals[3] & 0xffff0000u);
    H.z = (vals[4] & 0xffffu) | (vals[5] << 16);  L.z = (vals[4] >> 16) | (vals[5] & 0xffff0000u);
    H.w = (vals[6] & 0xffffu) | (vals[7] << 16);  L.w = (vals[6] >> 16) | (vals[7] & 0xffff0000u);
    *wBhi = H;
    *wBlo = L;
    __syncthreads();
    if (ic + 1 < NCH) issue(ic + 1);

    uint4 ah[4], al[4], bh[2], bl[2];
    #pragma unroll
    for (int mf = 0; mf < 4; ++mf) { ah[mf] = *pAhi[mf]; al[mf] = *pAlo[mf]; }
    #pragma unroll
    for (int nf = 0; nf < 2; ++nf) { bh[nf] = *pBhi[nf]; bl[nf] = *pBlo[nf]; }

    #pragma unroll
    for (int mf = 0; mf < 4; ++mf)
      #pragma unroll
      for (int nf = 0; nf < 2; ++nf) mfma_bf16(acc[mf][nf], ah[mf], bh[nf]);
    #pragma unroll
    for (int mf = 0; mf < 4; ++mf)
      #pragma unroll
      for (int nf = 0; nf < 2; ++nf) mfma_bf16(acc[mf][nf], ah[mf], bl[nf]);
    #pragma unroll
    for (int mf = 0; mf < 4; ++mf)
      #pragma unroll
      for (int nf = 0; nf < 2; ++nf) mfma_bf16(acc[mf][nf], al[mf], bh[nf]);
  }

  // epilogue: bias add, bf16x2 split, store into tiled feature layout
  // token = b*4096 + t*256 + hb*128 + n_l; tokb = token>>7 = b*32 + t*2 + hb; row = n_l
  const int lr4 = (lane >> 4) * 4;
  const int tokb = b * 32 + t * 2 + hb;
  #pragma unroll
  for (int mf = 0; mf < 4; ++mf) {
    const int co0g = cb * 128 + wm * 64 + mf * 16 + lr4;
    const float4 bv = *(const float4*)(bias + co0g);
    const int kc = co0g >> 5, kq = (co0g >> 3) & 3, j0 = co0g & 7;
    #pragma unroll
    for (int nf = 0; nf < 2; ++nf) {
      const int n_l = wn * 32 + nf * 16 + lc;
      const size_t off = (size_t)(tokb * 16 + kc) * 4096 + kq * 1024 + n_l * 8 + j0;
      unsigned int p0 = splitpack(acc[mf][nf][0] + bv.x);
      unsigned int p1 = splitpack(acc[mf][nf][1] + bv.y);
      unsigned int p2 = splitpack(acc[mf][nf][2] + bv.z);
      unsigned int p3 = splitpack(acc[mf][nf][3] + bv.w);
      ushort4 h4, l4;
      h4.x = (unsigned short)(p0 & 0xffffu); l4.x = (unsigned short)(p0 >> 16);
      h4.y = (unsigned short)(p1 & 0xffffu); l4.y = (unsigned short)(p1 >> 16);
      h4.z = (unsigned short)(p2 & 0xffffu); l4.z = (unsigned short)(p2 >> 16);
      h4.w = (unsigned short)(p3 & 0xffffu); l4.w = (unsigned short)(p3 >> 16);
      *(ushort4*)(fhi + off) = h4;
      *(ushort4*)(flo + off) = l4;
    }
  }
}

// ---------------- VQ as MFMA GEMM (bf16x2, 3 products) + fused argmin ----------------
__global__ __launch_bounds__(512) void vq_mfma_k(
    const unsigned short* __restrict__ fhi, const unsigned short* __restrict__ flo,
    const unsigned short* __restrict__ cbhi, const unsigned short* __restrict__ cblo,
    const float* __restrict__ c2,
    float* __restrict__ pval, int* __restrict__ pidx) {
  __shared__ __align__(16) unsigned short lds[16384];

  const int tid  = threadIdx.x;
  const int lane = tid & 63;
  const int wid  = tid >> 6;           // 8 waves: 2(M over v) x 4(N over tokens)
  const int wm   = wid >> 2, wn = wid & 3;
  const int vb = blockIdx.x;           // 64 v-blocks of 128
  const int tb = blockIdx.y;           // 64 token-blocks of 128
  const int v0 = vb * 128, tok0 = tb * 128;

  const int lc = lane & 15, kgl = lane >> 4;
  const uint4* pAhi[4]; const uint4* pAlo[4];
  #pragma unroll
  for (int mf = 0; mf < 4; ++mf) {
    const int off = kgl * 1024 + (wm * 64 + mf * 16 + lc) * 8;
    pAhi[mf] = (const uint4*)&lds[off];
    pAlo[mf] = (const uint4*)&lds[4096 + off];
  }
  const uint4* pBhi[2]; const uint4* pBlo[2];
  #pragma unroll
  for (int nf = 0; nf < 2; ++nf) {
    const int off = kgl * 1024 + (wn * 32 + nf * 16 + lc) * 8;
    pBhi[nf] = (const uint4*)&lds[8192 + off];
    pBlo[nf] = (const uint4*)&lds[12288 + off];
  }
  uint4* wAhi = (uint4*)&lds[tid * 8];
  uint4* wAlo = (uint4*)&lds[4096 + tid * 8];
  uint4* wBhi = (uint4*)&lds[8192 + tid * 8];
  uint4* wBlo = (uint4*)&lds[12288 + tid * 8];

  f32x4 acc[4][2];
  #pragma unroll
  for (int mf = 0; mf < 4; ++mf)
    #pragma unroll
    for (int nf = 0; nf < 2; ++nf) acc[mf][nf] = (f32x4)(0.f);

  uint4 cah, cal, fbh, fbl;
  auto issue = [&](int kc) {
    const size_t cboff = (size_t)(vb * 16 + kc) * 4096 + tid * 8;
    const size_t foff  = (size_t)(tb * 16 + kc) * 4096 + tid * 8;
    cah = *(const uint4*)(cbhi + cboff);
    cal = *(const uint4*)(cblo + cboff);
    fbh = *(const uint4*)(fhi + foff);
    fbl = *(const uint4*)(flo + foff);
  };

  issue(0);

  for (int kc = 0; kc < 16; ++kc) {
    __syncthreads();
    *wAhi = cah;
    *wAlo = cal;
    *wBhi = fbh;
    *wBlo = fbl;
    __syncthreads();
    if (kc + 1 < 16) issue(kc + 1);

    uint4 ah[4], al[4], bh[2], bl[2];
    #pragma unroll
    for (int mf = 0; mf < 4; ++mf) { ah[mf] = *pAhi[mf]; al[mf] = *pAlo[mf]; }
    #pragma unroll
    for (int nf = 0; nf < 2; ++nf) { bh[nf] = *pBhi[nf]; bl[nf] = *pBlo[nf]; }

    #pragma unroll
    for (int mf = 0; mf < 4; ++mf)
      #pragma unroll
      for (int nf = 0; nf < 2; ++nf) mfma_bf16(acc[mf][nf], ah[mf], bh[nf]);
    #pragma unroll
    for (int mf = 0; mf < 4; ++mf)
      #pragma unroll
      for (int nf = 0; nf < 2; ++nf) mfma_bf16(acc[mf][nf], ah[mf], bl[nf]);
    #pragma unroll
    for (int mf = 0; mf < 4; ++mf)
      #pragma unroll
      for (int nf = 0; nf < 2; ++nf) mfma_bf16(acc[mf][nf], al[mf], bh[nf]);
  }

  // fused dist + argmin. lane holds tokens (nf=0,1), v = v0 + wm*64 + mf*16 + kgl*4 + r
  float best[2]; int bidx[2];
  best[0] = best[1] = 3.4e38f; bidx[0] = bidx[1] = 0;
  #pragma unroll
  for (int mf = 0; mf < 4; ++mf) {
    float cc[4];
    *(float4*)cc = *(const float4*)(c2 + v0 + wm * 64 + mf * 16 + kgl * 4);
    #pragma unroll
    for (int nf = 0; nf < 2; ++nf) {
      #pragma unroll
      for (int r = 0; r < 4; ++r) {
        const float d = cc[r] - 2.f * acc[mf][nf][r];
        const int vg = v0 + wm * 64 + mf * 16 + kgl * 4 + r;
        if (d < best[nf] || (d == best[nf] && vg < bidx[nf])) { best[nf] = d; bidx[nf] = vg; }
      }
    }
  }
  #pragma unroll
  for (int off = 16; off <= 32; off <<= 1) {
    #pragma unroll
    for (int nf = 0; nf < 2; ++nf) {
      const float ov = __shfl_xor(best[nf], off);
      const int   oi = __shfl_xor(bidx[nf], off);
      if (ov < best[nf] || (ov == best[nf] && oi < bidx[nf])) { best[nf] = ov; bidx[nf] = oi; }
    }
  }
  if (lane < 16) {
    #pragma unroll
    for (int nf = 0; nf < 2; ++nf) {
      const int tok = tok0 + wn * 32 + nf * 16 + lane;
      const int slot = vb * 2 + wm;          // ascending in v
      pval[(size_t)tok * 128 + slot] = best[nf];
      pidx[(size_t)tok * 128 + slot] = bidx[nf];
    }
  }
}

__global__ void vq_reduce_k(const float* __restrict__ pval, const int* __restrict__ pidx,
                            int* __restrict__ tokens, float* __restrict__ out_tok) {
  const int tok = blockIdx.x * blockDim.x + threadIdx.x;  // 8192
  float best = 3.4e38f; int bi = 0;
  for (int s = 0; s < 128; ++s) {
    const float v = pval[(size_t)tok * 128 + s];
    const int idx = pidx[(size_t)tok * 128 + s];
    if (v < best || (v == best && idx < bi)) { best = v; bi = idx; }
  }
  tokens[tok] = bi;
  out_tok[tok] = (float)bi;
}

__global__ void gather_k(const int* __restrict__ tokens, const float* __restrict__ emb,
                         float* __restrict__ out) {
  const int i = blockIdx.x * blockDim.x + threadIdx.x;  // 1,048,576 float4s
  const int n = i >> 7;
  const int c4 = (i & 127) * 4;
  const int tk = tokens[n];
  float4 v = *(const float4*)(emb + (size_t)tk * 512 + c4);
  *(float4*)(out + (size_t)n * 512 + c4) = v;
}

extern "C" void kernel_launch(void* const* d_in, const int* in_sizes, int n_in,
                              void* d_out, int out_size, void* d_ws, size_t ws_size,
                              hipStream_t stream) {
  const float* video = (const float*)d_in[0];
  const float* w1 = (const float*)d_in[1];
  const float* b1 = (const float*)d_in[2];
  const float* w2 = (const float*)d_in[3];
  const float* b2 = (const float*)d_in[4];
  const float* w3 = (const float*)d_in[5];
  const float* b3 = (const float*)d_in[6];
  const float* cb  = (const float*)d_in[7];
  const float* emb = (const float*)d_in[8];

  // ---- workspace layout (float offsets) ----
  // region A [0 .. 16,777,216): h1; dead after conv2 ->
  //    h2p u32 [0 .. 9,469,952)   (dead after conv3 -> pval/pidx/tokens reuse front)
  //      pval   [0 .. 1,048,576)
  //      pidx   [1,048,576 .. 2,097,152)
  //      tokens [2,097,152 .. 2,099,200)
  //    fhi ushort [9,469,952 .. 11,567,104)   (tiled features hi)
  //    flo ushort [11,567,104 .. 13,664,256)
  //    c2         [13,664,256 .. 13,672,448)
  // region B [16,777,216 .. 25,165,824): h2; dead after split_h2 ->
  //    cbhi ushort [16,777,216 .. 18,874,368)
  //    cblo ushort [18,874,368 .. 20,971,520)
  // d_out scratch for split-w3 tiles until vq_reduce/gather overwrite it.
  float* ws = (float*)d_ws;
  float* h1   = ws;
  unsigned int* h2p = (unsigned int*)ws;
  float* pval = ws;                       // reuses dead h2p space
  int*   pidx = (int*)(ws + 1048576);
  int*   tokens = (int*)(ws + 2097152);
  unsigned short* fhi = (unsigned short*)(ws + 9469952);
  unsigned short* flo = (unsigned short*)(ws + 11567104);
  float* c2v  = ws + 13664256;
  float* h2   = ws + 16777216;
  unsigned short* cbhi = (unsigned short*)(ws + 16777216);
  unsigned short* cblo = (unsigned short*)(ws + 18874368);
  unsigned short* whi = (unsigned short*)d_out;   // 3,538,944 ushorts
  unsigned short* wlo = whi + 3538944;            // 3,538,944 ushorts
  float* out_tok = (float*)d_out;
  float* out_emb = (float*)d_out + 8192;

  hipLaunchKernelGGL((conv3d_s122_k<3, 128, 128, 128, 64, 64, 8, true>),
                     dim3(4, 16, 32), dim3(16, 16), 0, stream, video, w1, b1, h1);
  hipLaunchKernelGGL((conv3d_s122_k<128, 64, 64, 256, 32, 32, 8, true>),
                     dim3(1, 32, 32), dim3(8, 32), 0, stream, h1, w2, b2, h2);
  // h1 dead; build bf16x2 parity planes of h2 into region A
  hipLaunchKernelGGL(split_h2_k, dim3(36992), dim3(256), 0, stream, h2, h2p);
  // w3 -> MFMA tiles (into d_out scratch)
  hipLaunchKernelGGL(split_w3_k, dim3(13824), dim3(256), 0, stream, w3, whi, wlo);
  // h2 dead from here; tiled codebook reuses its space
  hipLaunchKernelGGL(split_cb_k, dim3(16384), dim3(256), 0, stream, cb, cbhi, cblo);
  hipLaunchKernelGGL(c2_k, dim3(2048), dim3(256), 0, stream, cb, c2v);
  // conv3 on matrix cores -> tiled bf16x2 features
  hipLaunchKernelGGL(conv3_mfma_k, dim3(4, 2, 32), dim3(512), 0, stream,
                     h2p, whi, wlo, b3, fhi, flo);
  // VQ on matrix cores (h2p dead; pval/pidx reuse its space)
  hipLaunchKernelGGL(vq_mfma_k, dim3(64, 64), dim3(512), 0, stream,
                     fhi, flo, cbhi, cblo, c2v, pval, pidx);
  hipLaunchKernelGGL(vq_reduce_k, dim3(32), dim3(256), 0, stream, pval, pidx, tokens, out_tok);
  hipLaunchKernelGGL(gather_k, dim3(4096), dim3(256), 0, stream, tokens, emb, out_emb);
}

// Round 4
// 827.404 us; speedup vs baseline: 3.9284x; 1.7511x over previous
//
#include <hip/hip_runtime.h>

typedef __bf16 bf16x8 __attribute__((ext_vector_type(8)));
typedef float  f32x4  __attribute__((ext_vector_type(4)));

// ---------------- bf16x2 split helper: pack(hi | lo<<16) ----------------
__device__ __forceinline__ unsigned int splitpack(float x) {
  unsigned int u = __float_as_uint(x);
  unsigned int hi = (u + 0x7fffu + ((u >> 16) & 1u)) >> 16;
  float l = x - __uint_as_float(hi << 16);
  unsigned int ul = __float_as_uint(l);
  unsigned int lo = (ul + 0x7fffu + ((ul >> 16) & 1u)) >> 16;
  return hi | (lo << 16);
}

__device__ __forceinline__ void mfma_bf16(f32x4& d, uint4 a, uint4 b) {
  d = __builtin_amdgcn_mfma_f32_16x16x32_bf16(
        __builtin_bit_cast(bf16x8, a), __builtin_bit_cast(bf16x8, b), d, 0, 0, 0);
}

// ---------------- conv1: VALU conv, epilogue writes parity bf16x2 planes ----------------
// h1p[(b*128+ci)*16+t][pl(=ph*2+pw)][r*32+c]  (compact: r=h>>1, ph=h&1; c=w>>1, pw=w&1)
__global__ void conv1_k(const float* __restrict__ in, const float* __restrict__ wgt,
                        const float* __restrict__ bias, unsigned int* __restrict__ h1p) {
  const int tx = threadIdx.x;          // 0..15
  const int w0 = tx * 4;
  const int h  = blockIdx.x * 16 + threadIdx.y;  // 0..63
  const int co0 = blockIdx.y * 8;
  const int bz = blockIdx.z;
  const int b = bz >> 4, t = bz & 15;

  float acc[8][4];
  #pragma unroll
  for (int i = 0; i < 8; ++i) {
    const float bv = bias[co0 + i];
    #pragma unroll
    for (int j = 0; j < 4; ++j) acc[i][j] = bv;
  }
  const int cs = 2 * w0 - 2;

  for (int ci = 0; ci < 3; ++ci) {
    const float* inc = in + (size_t)((b * 3 + ci) * 16) * (128 * 128);
    const float* wc  = wgt + ((size_t)co0 * 3 + ci) * 27;
    #pragma unroll
    for (int kd = 0; kd < 3; ++kd) {
      const int t2 = t - 1 + kd;
      if (t2 < 0 || t2 >= 16) continue;
      const float* ip = inc + t2 * (128 * 128);
      #pragma unroll
      for (int kh = 0; kh < 3; ++kh) {
        const int hh = 2 * h - 1 + kh;
        float v[10];
        if (hh >= 0) {
          const float* r = ip + hh * 128 + cs;
          if (cs >= 0) { float2 u = *(const float2*)r; v[0] = u.x; v[1] = u.y; }
          else         { v[0] = 0.f; v[1] = 0.f; }
          float2 u1 = *(const float2*)(r + 2); v[2] = u1.x; v[3] = u1.y;
          float2 u2 = *(const float2*)(r + 4); v[4] = u2.x; v[5] = u2.y;
          float2 u3 = *(const float2*)(r + 6); v[6] = u3.x; v[7] = u3.y;
          float2 u4 = *(const float2*)(r + 8); v[8] = u4.x; v[9] = u4.y;
        } else {
          #pragma unroll
          for (int z = 0; z < 10; ++z) v[z] = 0.f;
        }
        #pragma unroll
        for (int i = 0; i < 8; ++i) {
          const float* wp = wc + (size_t)i * (3 * 27) + kd * 9 + kh * 3;
          const float wa = wp[0], wb = wp[1], wcc = wp[2];
          #pragma unroll
          for (int wi = 0; wi < 4; ++wi) {
            acc[i][wi] = fmaf(v[1 + 2*wi], wa,  acc[i][wi]);
            acc[i][wi] = fmaf(v[2 + 2*wi], wb,  acc[i][wi]);
            acc[i][wi] = fmaf(v[3 + 2*wi], wcc, acc[i][wi]);
          }
        }
      }
    }
  }
  const int ph = h & 1, rr = h >> 1, cc0 = tx * 2;
  #pragma unroll
  for (int i = 0; i < 8; ++i) {
    unsigned int p0 = splitpack(fmaxf(acc[i][0], 0.f));
    unsigned int p1 = splitpack(fmaxf(acc[i][1], 0.f));
    unsigned int p2 = splitpack(fmaxf(acc[i][2], 0.f));
    unsigned int p3 = splitpack(fmaxf(acc[i][3], 0.f));
    const size_t base = ((size_t)((b * 128 + co0 + i) * 16 + t)) * 4096 + ph * 2048 + rr * 32 + cc0;
    *(uint2*)(h1p + base)        = make_uint2(p0, p2);   // plane pw=0
    *(uint2*)(h1p + base + 1024) = make_uint2(p1, p3);   // plane pw=1
  }
}

// ---------------- w2 -> MFMA tiles [tap27][cic4][cbk2][kg4][col128][j8] ----------------
__global__ void split_w2_k(const float* __restrict__ w2, unsigned short* __restrict__ whi,
                           unsigned short* __restrict__ wlo) {
  unsigned int o = blockIdx.x * 256u + threadIdx.x;      // grid exact: 3456*256
  unsigned int j   = o & 7u;
  unsigned int col = (o >> 3) & 127u;
  unsigned int kg  = (o >> 10) & 3u;
  unsigned int cbk = (o >> 12) & 1u;
  unsigned int cic = (o >> 13) & 3u;
  unsigned int tap = o >> 15;
  unsigned int co = cbk * 128u + col, ci = cic * 32u + kg * 8u + j;
  float x = w2[((size_t)co * 128u + ci) * 27u + tap];
  unsigned int p = splitpack(x);
  whi[o] = (unsigned short)(p & 0xffffu);
  wlo[o] = (unsigned short)(p >> 16);
}

// ---------------- w3 -> MFMA tiles [tap27][cic8][cb4][kg4][col128][j8] ----------------
__global__ void split_w3_k(const float* __restrict__ w3, unsigned short* __restrict__ whi,
                           unsigned short* __restrict__ wlo) {
  unsigned int o = blockIdx.x * 256u + threadIdx.x;      // grid exact: 13824*256 = 27<<17
  unsigned int j   = o & 7u;
  unsigned int col = (o >> 3) & 127u;
  unsigned int kg  = (o >> 10) & 3u;
  unsigned int cb  = (o >> 12) & 3u;
  unsigned int cic = (o >> 14) & 7u;
  unsigned int tap = o >> 17;
  unsigned int co = cb * 128u + col, ci = cic * 32u + kg * 8u + j;
  float x = w3[((size_t)co * 256u + ci) * 27u + tap];
  unsigned int p = splitpack(x);
  whi[o] = (unsigned short)(p & 0xffffu);
  wlo[o] = (unsigned short)(p >> 16);
}

// ---------------- codebook -> tiled hi/lo ----------------
__global__ void split_cb_k(const float* __restrict__ cb, unsigned short* __restrict__ cbhi,
                           unsigned short* __restrict__ cblo) {
  unsigned int o = blockIdx.x * 256u + threadIdx.x;      // grid exact: 16384*256 = 2^22
  unsigned int j   = o & 7u;
  unsigned int row = (o >> 3) & 127u;
  unsigned int kq  = (o >> 10) & 3u;
  unsigned int kc  = (o >> 12) & 15u;
  unsigned int vb  = o >> 16;
  unsigned int v = vb * 128u + row, k = kc * 32u + kq * 8u + j;
  float x = cb[(size_t)v * 512u + k];
  unsigned int p = splitpack(x);
  cbhi[o] = (unsigned short)(p & 0xffffu);
  cblo[o] = (unsigned short)(p >> 16);
}

// ---------------- codebook squared norms ----------------
__global__ void c2_k(const float* __restrict__ cb, float* __restrict__ c2) {
  const int wid = threadIdx.x >> 6, lane = threadIdx.x & 63;
  const int v = blockIdx.x * 4 + wid;
  const float* row = cb + (size_t)v * 512 + lane * 8;
  float4 a = *(const float4*)row, b = *(const float4*)(row + 4);
  float s = a.x*a.x + a.y*a.y + a.z*a.z + a.w*a.w
          + b.x*b.x + b.y*b.y + b.z*b.z + b.w*b.w;
  #pragma unroll
  for (int off = 32; off; off >>= 1) s += __shfl_down(s, off);
  if (lane == 0) c2[v] = s;
}

// ---------------- conv2 as implicit-GEMM MFMA (bf16x2), planes in -> planes out --------
#define NCH2 108   // 27 taps * 4 ci-chunks of 32
__global__ __launch_bounds__(512) void conv2_mfma_k(
    const unsigned int* __restrict__ xp,    // h1p planes (packed hi|lo)
    const unsigned short* __restrict__ whi, const unsigned short* __restrict__ wlo,
    const float* __restrict__ bias,
    unsigned int* __restrict__ h2p) {       // compact planes out
  __shared__ __align__(16) unsigned short lds[16384];

  const int tid  = threadIdx.x;
  const int lane = tid & 63;
  const int wid  = tid >> 6;           // 8 waves: 2(M) x 4(N)
  const int wm   = wid >> 2, wn = wid & 3;
  const int cbk = blockIdx.x;          // 0..1 co block
  const int nb  = blockIdx.y;          // 0..7 h-strip of 4 rows
  const int bt  = blockIdx.z;          // 0..31
  const int b = bt >> 4, t = bt & 15;

  const int skg = tid >> 7;            // 0..3
  const int sn  = tid & 127;           // token
  const int s_hout = nb * 4 + (sn >> 5);
  const int s_wout = sn & 31;
  const int base_ci = b * 8388608 + skg * 524288;

  const int lc = lane & 15, kgl = lane >> 4;
  const uint4* pAhi[4]; const uint4* pAlo[4];
  #pragma unroll
  for (int mf = 0; mf < 4; ++mf) {
    const int off = kgl * 1024 + (wm * 64 + mf * 16 + lc) * 8;
    pAhi[mf] = (const uint4*)&lds[off];
    pAlo[mf] = (const uint4*)&lds[4096 + off];
  }
  const uint4* pBhi[2]; const uint4* pBlo[2];
  #pragma unroll
  for (int nf = 0; nf < 2; ++nf) {
    const int off = kgl * 1024 + (wn * 32 + nf * 16 + lc) * 8;
    pBhi[nf] = (const uint4*)&lds[8192 + off];
    pBlo[nf] = (const uint4*)&lds[12288 + off];
  }
  uint4* wAhi = (uint4*)&lds[tid * 8];
  uint4* wAlo = (uint4*)&lds[4096 + tid * 8];
  uint4* wBhi = (uint4*)&lds[8192  + (skg * 128 + sn) * 8];
  uint4* wBlo = (uint4*)&lds[12288 + (skg * 128 + sn) * 8];

  f32x4 acc[4][2];
  #pragma unroll
  for (int mf = 0; mf < 4; ++mf)
    #pragma unroll
    for (int nf = 0; nf < 2; ++nf) acc[mf][nf] = (f32x4)(0.f);

  uint4 avh, avl;
  unsigned int vals[8];

  auto issue = [&](int ic) {
    const int tap = ic >> 2, cic = ic & 3;
    const int kd = tap / 9, r9 = tap % 9;
    const int kh = r9 / 3, kw = r9 % 3;
    const int tt = t + kd - 1;
    const int pl = ((kh != 1) ? 2 : 0) + ((kw != 1) ? 1 : 0);
    const int r  = s_hout + (kh != 0) - 1;
    const int c  = s_wout + (kw != 0) - 1;
    const bool oob = (tt < 0) || (tt > 15) || (r < 0) || (c < 0);
    const int idx0 = base_ci + cic * 2097152 + tt * 4096 + pl * 1024 + r * 32 + c;
    #pragma unroll
    for (int j = 0; j < 8; ++j) {
      unsigned int sidx = oob ? 0u : (unsigned int)(idx0 + j * 65536);
      unsigned int v = xp[sidx];
      vals[j] = oob ? 0u : v;
    }
    const size_t slab = ((size_t)((tap * 4 + cic) * 2 + cbk)) << 12;
    avh = *(const uint4*)(whi + slab + tid * 8);
    avl = *(const uint4*)(wlo + slab + tid * 8);
  };

  issue(0);

  for (int ic = 0; ic < NCH2; ++ic) {
    __syncthreads();
    *wAhi = avh;
    *wAlo = avl;
    uint4 H, L;
    H.x = (vals[0] & 0xffffu) | (vals[1] << 16);  L.x = (vals[0] >> 16) | (vals[1] & 0xffff0000u);
    H.y = (vals[2] & 0xffffu) | (vals[3] << 16);  L.y = (vals[2] >> 16) | (vals[3] & 0xffff0000u);
    H.z = (vals[4] & 0xffffu) | (vals[5] << 16);  L.z = (vals[4] >> 16) | (vals[5] & 0xffff0000u);
    H.w = (vals[6] & 0xffffu) | (vals[7] << 16);  L.w = (vals[6] >> 16) | (vals[7] & 0xffff0000u);
    *wBhi = H;
    *wBlo = L;
    __syncthreads();
    if (ic + 1 < NCH2) issue(ic + 1);

    uint4 ah[4], al[4], bh[2], bl[2];
    #pragma unroll
    for (int mf = 0; mf < 4; ++mf) { ah[mf] = *pAhi[mf]; al[mf] = *pAlo[mf]; }
    #pragma unroll
    for (int nf = 0; nf < 2; ++nf) { bh[nf] = *pBhi[nf]; bl[nf] = *pBlo[nf]; }

    #pragma unroll
    for (int mf = 0; mf < 4; ++mf)
      #pragma unroll
      for (int nf = 0; nf < 2; ++nf) mfma_bf16(acc[mf][nf], ah[mf], bh[nf]);
    #pragma unroll
    for (int mf = 0; mf < 4; ++mf)
      #pragma unroll
      for (int nf = 0; nf < 2; ++nf) mfma_bf16(acc[mf][nf], ah[mf], bl[nf]);
    #pragma unroll
    for (int mf = 0; mf < 4; ++mf)
      #pragma unroll
      for (int nf = 0; nf < 2; ++nf) mfma_bf16(acc[mf][nf], al[mf], bh[nf]);
  }

  // epilogue: bias + ReLU + splitpack, scatter into compact h2p planes
  const int lr4 = (lane >> 4) * 4;
  #pragma unroll
  for (int mf = 0; mf < 4; ++mf) {
    const int co0g = cbk * 128 + wm * 64 + mf * 16 + lr4;
    const float4 bv = *(const float4*)(bias + co0g);
    #pragma unroll
    for (int nf = 0; nf < 2; ++nf) {
      const int n_l = wn * 32 + nf * 16 + lc;
      const int h_out = nb * 4 + (n_l >> 5);
      const int w_out = n_l & 31;
      const int pl_o = ((h_out & 1) << 1) | (w_out & 1);
      const size_t sp = pl_o * 256 + (h_out >> 1) * 16 + (w_out >> 1);
      const float* bp = (const float*)&bv;
      #pragma unroll
      for (int r = 0; r < 4; ++r) {
        const int co = co0g + r;
        const float x = fmaxf(acc[mf][nf][r] + bp[r], 0.f);
        h2p[((size_t)((b * 256 + co) * 16 + t)) * 1024 + sp] = splitpack(x);
      }
    }
  }
}

// ---------------- conv3 as implicit-GEMM MFMA, compact planes in, tiled feats out ------
#define NCH 216   // 27 taps * 8 ci-chunks of 32
__global__ __launch_bounds__(512) void conv3_mfma_k(
    const unsigned int* __restrict__ xp,    // h2p compact planes
    const unsigned short* __restrict__ whi, const unsigned short* __restrict__ wlo,
    const float* __restrict__ bias,
    unsigned short* __restrict__ fhi, unsigned short* __restrict__ flo) {
  __shared__ __align__(16) unsigned short lds[16384];

  const int tid  = threadIdx.x;
  const int lane = tid & 63;
  const int wid  = tid >> 6;           // 8 waves: 2(M) x 4(N)
  const int wm   = wid >> 2, wn = wid & 3;
  const int cb = blockIdx.x;           // co block (128)
  const int hb = blockIdx.y;           // h half (8 rows)
  const int bt = blockIdx.z;           // b*16 + t
  const int b = bt >> 4, t = bt & 15;

  const int skg = tid >> 7;
  const int sn  = tid & 127;
  const int shn = hb * 8 + (sn >> 4);  // h_out 0..15
  const int swn = sn & 15;             // w_out
  const int base_ci = b * 4194304 + skg * 131072;

  const int lc = lane & 15, kgl = lane >> 4;
  const uint4* pAhi[4]; const uint4* pAlo[4];
  #pragma unroll
  for (int mf = 0; mf < 4; ++mf) {
    const int off = kgl * 1024 + (wm * 64 + mf * 16 + lc) * 8;
    pAhi[mf] = (const uint4*)&lds[off];
    pAlo[mf] = (const uint4*)&lds[4096 + off];
  }
  const uint4* pBhi[2]; const uint4* pBlo[2];
  #pragma unroll
  for (int nf = 0; nf < 2; ++nf) {
    const int off = kgl * 1024 + (wn * 32 + nf * 16 + lc) * 8;
    pBhi[nf] = (const uint4*)&lds[8192 + off];
    pBlo[nf] = (const uint4*)&lds[12288 + off];
  }
  uint4* wAhi = (uint4*)&lds[tid * 8];
  uint4* wAlo = (uint4*)&lds[4096 + tid * 8];
  uint4* wBhi = (uint4*)&lds[8192  + (skg * 128 + sn) * 8];
  uint4* wBlo = (uint4*)&lds[12288 + (skg * 128 + sn) * 8];

  f32x4 acc[4][2];
  #pragma unroll
  for (int mf = 0; mf < 4; ++mf)
    #pragma unroll
    for (int nf = 0; nf < 2; ++nf) acc[mf][nf] = (f32x4)(0.f);

  uint4 avh, avl;
  unsigned int vals[8];

  auto issue = [&](int ic) {
    const int tap = ic >> 3, cic = ic & 7;
    const int kd = tap / 9, r9 = tap % 9;
    const int kh = r9 / 3, kw = r9 % 3;
    const int tt = t + kd - 1;
    const int pl = ((kh != 1) ? 2 : 0) + ((kw != 1) ? 1 : 0);
    const int r  = shn + (kh != 0) - 1;
    const int c  = swn + (kw != 0) - 1;
    const bool oob = (tt < 0) || (tt > 15) || (r < 0) || (c < 0);
    const int idx0 = base_ci + cic * 524288 + tt * 1024 + pl * 256 + r * 16 + c;
    #pragma unroll
    for (int j = 0; j < 8; ++j) {
      unsigned int sidx = oob ? 0u : (unsigned int)(idx0 + j * 16384);
      unsigned int v = xp[sidx];
      vals[j] = oob ? 0u : v;
    }
    const size_t slab = ((size_t)((tap * 8 + cic) * 4 + cb)) << 12;
    avh = *(const uint4*)(whi + slab + tid * 8);
    avl = *(const uint4*)(wlo + slab + tid * 8);
  };

  issue(0);

  for (int ic = 0; ic < NCH; ++ic) {
    __syncthreads();
    *wAhi = avh;
    *wAlo = avl;
    uint4 H, L;
    H.x = (vals[0] & 0xffffu) | (vals[1] << 16);  L.x = (vals[0] >> 16) | (vals[1] & 0xffff0000u);
    H.y = (vals[2] & 0xffffu) | (vals[3] << 16);  L.y = (vals[2] >> 16) | (vals[3] & 0xffff0000u);
    H.z = (vals[4] & 0xffffu) | (vals[5] << 16);  L.z = (vals[4] >> 16) | (vals[5] & 0xffff0000u);
    H.w = (vals[6] & 0xffffu) | (vals[7] << 16);  L.w = (vals[6] >> 16) | (vals[7] & 0xffff0000u);
    *wBhi = H;
    *wBlo = L;
    __syncthreads();
    if (ic + 1 < NCH) issue(ic + 1);

    uint4 ah[4], al[4], bh[2], bl[2];
    #pragma unroll
    for (int mf = 0; mf < 4; ++mf) { ah[mf] = *pAhi[mf]; al[mf] = *pAlo[mf]; }
    #pragma unroll
    for (int nf = 0; nf < 2; ++nf) { bh[nf] = *pBhi[nf]; bl[nf] = *pBlo[nf]; }

    #pragma unroll
    for (int mf = 0; mf < 4; ++mf)
      #pragma unroll
      for (int nf = 0; nf < 2; ++nf) mfma_bf16(acc[mf][nf], ah[mf], bh[nf]);
    #pragma unroll
    for (int mf = 0; mf < 4; ++mf)
      #pragma unroll
      for (int nf = 0; nf < 2; ++nf) mfma_bf16(acc[mf][nf], ah[mf], bl[nf]);
    #pragma unroll
    for (int mf = 0; mf < 4; ++mf)
      #pragma unroll
      for (int nf = 0; nf < 2; ++nf) mfma_bf16(acc[mf][nf], al[mf], bh[nf]);
  }

  // epilogue: bias add, bf16x2 split, store into tiled feature layout
  const int lr4 = (lane >> 4) * 4;
  const int tokb = b * 32 + t * 2 + hb;
  #pragma unroll
  for (int mf = 0; mf < 4; ++mf) {
    const int co0g = cb * 128 + wm * 64 + mf * 16 + lr4;
    const float4 bv = *(const float4*)(bias + co0g);
    const int kc = co0g >> 5, kq = (co0g >> 3) & 3, j0 = co0g & 7;
    #pragma unroll
    for (int nf = 0; nf < 2; ++nf) {
      const int n_l = wn * 32 + nf * 16 + lc;
      const size_t off = (size_t)(tokb * 16 + kc) * 4096 + kq * 1024 + n_l * 8 + j0;
      unsigned int p0 = splitpack(acc[mf][nf][0] + bv.x);
      unsigned int p1 = splitpack(acc[mf][nf][1] + bv.y);
      unsigned int p2 = splitpack(acc[mf][nf][2] + bv.z);
      unsigned int p3 = splitpack(acc[mf][nf][3] + bv.w);
      ushort4 h4, l4;
      h4.x = (unsigned short)(p0 & 0xffffu); l4.x = (unsigned short)(p0 >> 16);
      h4.y = (unsigned short)(p1 & 0xffffu); l4.y = (unsigned short)(p1 >> 16);
      h4.z = (unsigned short)(p2 & 0xffffu); l4.z = (unsigned short)(p2 >> 16);
      h4.w = (unsigned short)(p3 & 0xffffu); l4.w = (unsigned short)(p3 >> 16);
      *(ushort4*)(fhi + off) = h4;
      *(ushort4*)(flo + off) = l4;
    }
  }
}

// ---------------- VQ as MFMA GEMM (bf16x2) + fused argmin ----------------
__global__ __launch_bounds__(512) void vq_mfma_k(
    const unsigned short* __restrict__ fhi, const unsigned short* __restrict__ flo,
    const unsigned short* __restrict__ cbhi, const unsigned short* __restrict__ cblo,
    const float* __restrict__ c2,
    float* __restrict__ pval, int* __restrict__ pidx) {
  __shared__ __align__(16) unsigned short lds[16384];

  const int tid  = threadIdx.x;
  const int lane = tid & 63;
  const int wid  = tid >> 6;
  const int wm   = wid >> 2, wn = wid & 3;
  const int vb = blockIdx.x;
  const int tb = blockIdx.y;
  const int v0 = vb * 128, tok0 = tb * 128;

  const int lc = lane & 15, kgl = lane >> 4;
  const uint4* pAhi[4]; const uint4* pAlo[4];
  #pragma unroll
  for (int mf = 0; mf < 4; ++mf) {
    const int off = kgl * 1024 + (wm * 64 + mf * 16 + lc) * 8;
    pAhi[mf] = (const uint4*)&lds[off];
    pAlo[mf] = (const uint4*)&lds[4096 + off];
  }
  const uint4* pBhi[2]; const uint4* pBlo[2];
  #pragma unroll
  for (int nf = 0; nf < 2; ++nf) {
    const int off = kgl * 1024 + (wn * 32 + nf * 16 + lc) * 8;
    pBhi[nf] = (const uint4*)&lds[8192 + off];
    pBlo[nf] = (const uint4*)&lds[12288 + off];
  }
  uint4* wAhi = (uint4*)&lds[tid * 8];
  uint4* wAlo = (uint4*)&lds[4096 + tid * 8];
  uint4* wBhi = (uint4*)&lds[8192 + tid * 8];
  uint4* wBlo = (uint4*)&lds[12288 + tid * 8];

  f32x4 acc[4][2];
  #pragma unroll
  for (int mf = 0; mf < 4; ++mf)
    #pragma unroll
    for (int nf = 0; nf < 2; ++nf) acc[mf][nf] = (f32x4)(0.f);

  uint4 cah, cal, fbh, fbl;
  auto issue = [&](int kc) {
    const size_t cboff = (size_t)(vb * 16 + kc) * 4096 + tid * 8;
    const size_t foff  = (size_t)(tb * 16 + kc) * 4096 + tid * 8;
    cah = *(const uint4*)(cbhi + cboff);
    cal = *(const uint4*)(cblo + cboff);
    fbh = *(const uint4*)(fhi + foff);
    fbl = *(const uint4*)(flo + foff);
  };

  issue(0);

  for (int kc = 0; kc < 16; ++kc) {
    __syncthreads();
    *wAhi = cah;
    *wAlo = cal;
    *wBhi = fbh;
    *wBlo = fbl;
    __syncthreads();
    if (kc + 1 < 16) issue(kc + 1);

    uint4 ah[4], al[4], bh[2], bl[2];
    #pragma unroll
    for (int mf = 0; mf < 4; ++mf) { ah[mf] = *pAhi[mf]; al[mf] = *pAlo[mf]; }
    #pragma unroll
    for (int nf = 0; nf < 2; ++nf) { bh[nf] = *pBhi[nf]; bl[nf] = *pBlo[nf]; }

    #pragma unroll
    for (int mf = 0; mf < 4; ++mf)
      #pragma unroll
      for (int nf = 0; nf < 2; ++nf) mfma_bf16(acc[mf][nf], ah[mf], bh[nf]);
    #pragma unroll
    for (int mf = 0; mf < 4; ++mf)
      #pragma unroll
      for (int nf = 0; nf < 2; ++nf) mfma_bf16(acc[mf][nf], ah[mf], bl[nf]);
    #pragma unroll
    for (int mf = 0; mf < 4; ++mf)
      #pragma unroll
      for (int nf = 0; nf < 2; ++nf) mfma_bf16(acc[mf][nf], al[mf], bh[nf]);
  }

  float best[2]; int bidx[2];
  best[0] = best[1] = 3.4e38f; bidx[0] = bidx[1] = 0;
  #pragma unroll
  for (int mf = 0; mf < 4; ++mf) {
    float cc[4];
    *(float4*)cc = *(const float4*)(c2 + v0 + wm * 64 + mf * 16 + kgl * 4);
    #pragma unroll
    for (int nf = 0; nf < 2; ++nf) {
      #pragma unroll
      for (int r = 0; r < 4; ++r) {
        const float d = cc[r] - 2.f * acc[mf][nf][r];
        const int vg = v0 + wm * 64 + mf * 16 + kgl * 4 + r;
        if (d < best[nf] || (d == best[nf] && vg < bidx[nf])) { best[nf] = d; bidx[nf] = vg; }
      }
    }
  }
  #pragma unroll
  for (int off = 16; off <= 32; off <<= 1) {
    #pragma unroll
    for (int nf = 0; nf < 2; ++nf) {
      const float ov = __shfl_xor(best[nf], off);
      const int   oi = __shfl_xor(bidx[nf], off);
      if (ov < best[nf] || (ov == best[nf] && oi < bidx[nf])) { best[nf] = ov; bidx[nf] = oi; }
    }
  }
  if (lane < 16) {
    #pragma unroll
    for (int nf = 0; nf < 2; ++nf) {
      const int tok = tok0 + wn * 32 + nf * 16 + lane;
      const int slot = vb * 2 + wm;
      pval[(size_t)tok * 128 + slot] = best[nf];
      pidx[(size_t)tok * 128 + slot] = bidx[nf];
    }
  }
}

__global__ void vq_reduce_k(const float* __restrict__ pval, const int* __restrict__ pidx,
                            int* __restrict__ tokens, float* __restrict__ out_tok) {
  const int tok = blockIdx.x * blockDim.x + threadIdx.x;  // 8192
  float best = 3.4e38f; int bi = 0;
  for (int s = 0; s < 128; ++s) {
    const float v = pval[(size_t)tok * 128 + s];
    const int idx = pidx[(size_t)tok * 128 + s];
    if (v < best || (v == best && idx < bi)) { best = v; bi = idx; }
  }
  tokens[tok] = bi;
  out_tok[tok] = (float)bi;
}

__global__ void gather_k(const int* __restrict__ tokens, const float* __restrict__ emb,
                         float* __restrict__ out) {
  const int i = blockIdx.x * blockDim.x + threadIdx.x;  // 1,048,576 float4s
  const int n = i >> 7;
  const int c4 = (i & 127) * 4;
  const int tk = tokens[n];
  float4 v = *(const float4*)(emb + (size_t)tk * 512 + c4);
  *(float4*)(out + (size_t)n * 512 + c4) = v;
}

extern "C" void kernel_launch(void* const* d_in, const int* in_sizes, int n_in,
                              void* d_out, int out_size, void* d_ws, size_t ws_size,
                              hipStream_t stream) {
  const float* video = (const float*)d_in[0];
  const float* w1 = (const float*)d_in[1];
  const float* b1 = (const float*)d_in[2];
  const float* w2 = (const float*)d_in[3];
  const float* b2 = (const float*)d_in[4];
  const float* w3 = (const float*)d_in[5];
  const float* b3 = (const float*)d_in[6];
  const float* cb  = (const float*)d_in[7];
  const float* emb = (const float*)d_in[8];

  // ---- workspace layout (float offsets) ----
  // h1p u32 [0 .. 16,777,216)           conv1 out planes (64 MiB); dead after conv2 ->
  //    fhi   ushort @ float [0 .. 2,097,152)
  //    flo   ushort @ float [2,097,152 .. 4,194,304)
  //    cbhi  ushort @ float [4,194,304 .. 6,291,456)
  //    cblo  ushort @ float [6,291,456 .. 8,388,608)
  //    c2    @ [8,388,608 .. 8,396,800)
  //    pval  @ [8,396,800 .. 9,445,376)
  //    pidx  @ [9,445,376 .. 10,493,952)
  //    tokens@ [10,493,952 .. 10,502,144)
  // h2p u32 [16,777,216 .. 25,165,824)  conv2 out planes (32 MiB)
  // d_out: w2 tiles, then w3 tiles (overwritten by final outputs)
  float* ws = (float*)d_ws;
  unsigned int* h1p = (unsigned int*)ws;
  unsigned short* fhi = (unsigned short*)(ws);
  unsigned short* flo = (unsigned short*)(ws + 2097152);
  unsigned short* cbhi = (unsigned short*)(ws + 4194304);
  unsigned short* cblo = (unsigned short*)(ws + 6291456);
  float* c2v  = ws + 8388608;
  float* pval = ws + 8396800;
  int*   pidx = (int*)(ws + 9445376);
  int*   tokens = (int*)(ws + 10493952);
  unsigned int* h2p = (unsigned int*)(ws + 16777216);
  unsigned short* w2hi = (unsigned short*)d_out;  //   884,736 ushorts
  unsigned short* w2lo = w2hi + 884736;
  unsigned short* w3hi = (unsigned short*)d_out;  // 3,538,944 ushorts
  unsigned short* w3lo = w3hi + 3538944;
  float* out_tok = (float*)d_out;
  float* out_emb = (float*)d_out + 8192;

  hipLaunchKernelGGL(conv1_k, dim3(4, 16, 32), dim3(16, 16), 0, stream, video, w1, b1, h1p);
  hipLaunchKernelGGL(split_w2_k, dim3(3456), dim3(256), 0, stream, w2, w2hi, w2lo);
  hipLaunchKernelGGL(conv2_mfma_k, dim3(2, 8, 32), dim3(512), 0, stream,
                     h1p, w2hi, w2lo, b2, h2p);
  // h1p dead; d_out w2 tiles dead -> w3 tiles
  hipLaunchKernelGGL(split_w3_k, dim3(13824), dim3(256), 0, stream, w3, w3hi, w3lo);
  hipLaunchKernelGGL(split_cb_k, dim3(16384), dim3(256), 0, stream, cb, cbhi, cblo);
  hipLaunchKernelGGL(c2_k, dim3(2048), dim3(256), 0, stream, cb, c2v);
  hipLaunchKernelGGL(conv3_mfma_k, dim3(4, 2, 32), dim3(512), 0, stream,
                     h2p, w3hi, w3lo, b3, fhi, flo);
  hipLaunchKernelGGL(vq_mfma_k, dim3(64, 64), dim3(512), 0, stream,
                     fhi, flo, cbhi, cblo, c2v, pval, pidx);
  hipLaunchKernelGGL(vq_reduce_k, dim3(32), dim3(256), 0, stream, pval, pidx, tokens, out_tok);
  hipLaunchKernelGGL(gather_k, dim3(4096), dim3(256), 0, stream, tokens, emb, out_emb);
}

// Round 5
// 742.528 us; speedup vs baseline: 4.3774x; 1.1143x over previous
//
#include <hip/hip_runtime.h>

typedef __bf16 bf16x8 __attribute__((ext_vector_type(8)));
typedef float  f32x4  __attribute__((ext_vector_type(4)));

// ---------------- bf16x2 split helper: pack(hi | lo<<16) ----------------
__device__ __forceinline__ unsigned int splitpack(float x) {
  unsigned int u = __float_as_uint(x);
  unsigned int hi = (u + 0x7fffu + ((u >> 16) & 1u)) >> 16;
  float l = x - __uint_as_float(hi << 16);
  unsigned int ul = __float_as_uint(l);
  unsigned int lo = (ul + 0x7fffu + ((ul >> 16) & 1u)) >> 16;
  return hi | (lo << 16);
}

__device__ __forceinline__ void mfma_bf16(f32x4& d, uint4 a, uint4 b) {
  d = __builtin_amdgcn_mfma_f32_16x16x32_bf16(
        __builtin_bit_cast(bf16x8, a), __builtin_bit_cast(bf16x8, b), d, 0, 0, 0);
}

// ======== layouts ========
// h1p u32: IDX1(b,g,t,pl,r,c,j) = b*8388608 + g*524288 + t*32768 + pl*8192 + (r*32+c)*8 + j
//          g = ci>>3 (16), j = ci&7, pl = ph*2+pw, r,c in [0,32)
// h2p u32: IDX2(b,g,t,pl,r,c,j) = b*4194304 + g*131072 + t*8192 + pl*2048 + (r*16+c)*8 + j
//          g = co>>3 (32), j = co&7, r,c in [0,16)

// ---------------- conv1: VALU conv, epilogue writes j-grouped parity planes ------------
__global__ void conv1_k(const float* __restrict__ in, const float* __restrict__ wgt,
                        const float* __restrict__ bias, unsigned int* __restrict__ h1p) {
  const int tx = threadIdx.x;          // 0..15
  const int w0 = tx * 4;
  const int h  = blockIdx.x * 16 + threadIdx.y;  // 0..63
  const int co0 = blockIdx.y * 8;
  const int bz = blockIdx.z;
  const int b = bz >> 4, t = bz & 15;

  float acc[8][4];
  #pragma unroll
  for (int i = 0; i < 8; ++i) {
    const float bv = bias[co0 + i];
    #pragma unroll
    for (int j = 0; j < 4; ++j) acc[i][j] = bv;
  }
  const int cs = 2 * w0 - 2;

  for (int ci = 0; ci < 3; ++ci) {
    const float* inc = in + (size_t)((b * 3 + ci) * 16) * (128 * 128);
    const float* wc  = wgt + ((size_t)co0 * 3 + ci) * 27;
    #pragma unroll
    for (int kd = 0; kd < 3; ++kd) {
      const int t2 = t - 1 + kd;
      if (t2 < 0 || t2 >= 16) continue;
      const float* ip = inc + t2 * (128 * 128);
      #pragma unroll
      for (int kh = 0; kh < 3; ++kh) {
        const int hh = 2 * h - 1 + kh;
        float v[10];
        if (hh >= 0) {
          const float* r = ip + hh * 128 + cs;
          if (cs >= 0) { float2 u = *(const float2*)r; v[0] = u.x; v[1] = u.y; }
          else         { v[0] = 0.f; v[1] = 0.f; }
          float2 u1 = *(const float2*)(r + 2); v[2] = u1.x; v[3] = u1.y;
          float2 u2 = *(const float2*)(r + 4); v[4] = u2.x; v[5] = u2.y;
          float2 u3 = *(const float2*)(r + 6); v[6] = u3.x; v[7] = u3.y;
          float2 u4 = *(const float2*)(r + 8); v[8] = u4.x; v[9] = u4.y;
        } else {
          #pragma unroll
          for (int z = 0; z < 10; ++z) v[z] = 0.f;
        }
        #pragma unroll
        for (int i = 0; i < 8; ++i) {
          const float* wp = wc + (size_t)i * (3 * 27) + kd * 9 + kh * 3;
          const float wa = wp[0], wb = wp[1], wcc = wp[2];
          #pragma unroll
          for (int wi = 0; wi < 4; ++wi) {
            acc[i][wi] = fmaf(v[1 + 2*wi], wa,  acc[i][wi]);
            acc[i][wi] = fmaf(v[2 + 2*wi], wb,  acc[i][wi]);
            acc[i][wi] = fmaf(v[3 + 2*wi], wcc, acc[i][wi]);
          }
        }
      }
    }
  }
  const int ph = h & 1, rr = h >> 1, cc0 = tx * 2;
  const size_t base0 = (size_t)b * 8388608 + (size_t)blockIdx.y * 524288
                     + (size_t)t * 32768 + (size_t)(ph * 2) * 8192 + (size_t)rr * 256;
  #pragma unroll
  for (int i = 0; i < 8; ++i) {
    unsigned int p0 = splitpack(fmaxf(acc[i][0], 0.f));   // w=w0   -> pw=0, c=cc0
    unsigned int p1 = splitpack(fmaxf(acc[i][1], 0.f));   // w=w0+1 -> pw=1, c=cc0
    unsigned int p2 = splitpack(fmaxf(acc[i][2], 0.f));   // w=w0+2 -> pw=0, c=cc0+1
    unsigned int p3 = splitpack(fmaxf(acc[i][3], 0.f));   // w=w0+3 -> pw=1, c=cc0+1
    h1p[base0 + cc0 * 8 + i]              = p0;
    h1p[base0 + 8192 + cc0 * 8 + i]       = p1;
    h1p[base0 + (cc0 + 1) * 8 + i]        = p2;
    h1p[base0 + 8192 + (cc0 + 1) * 8 + i] = p3;
  }
}

// ---------------- w2 -> MFMA tiles [tap27][cic4][cbk2][kg4][col128][j8] ----------------
__global__ void split_w2_k(const float* __restrict__ w2, unsigned short* __restrict__ whi,
                           unsigned short* __restrict__ wlo) {
  unsigned int o = blockIdx.x * 256u + threadIdx.x;      // grid exact: 3456*256
  unsigned int j   = o & 7u;
  unsigned int col = (o >> 3) & 127u;
  unsigned int kg  = (o >> 10) & 3u;
  unsigned int cbk = (o >> 12) & 1u;
  unsigned int cic = (o >> 13) & 3u;
  unsigned int tap = o >> 15;
  unsigned int co = cbk * 128u + col, ci = cic * 32u + kg * 8u + j;
  float x = w2[((size_t)co * 128u + ci) * 27u + tap];
  unsigned int p = splitpack(x);
  whi[o] = (unsigned short)(p & 0xffffu);
  wlo[o] = (unsigned short)(p >> 16);
}

// ---------------- w3 -> MFMA tiles [tap27][cic8][cb4][kg4][col128][j8] ----------------
__global__ void split_w3_k(const float* __restrict__ w3, unsigned short* __restrict__ whi,
                           unsigned short* __restrict__ wlo) {
  unsigned int o = blockIdx.x * 256u + threadIdx.x;      // grid exact: 13824*256 = 27<<17
  unsigned int j   = o & 7u;
  unsigned int col = (o >> 3) & 127u;
  unsigned int kg  = (o >> 10) & 3u;
  unsigned int cb  = (o >> 12) & 3u;
  unsigned int cic = (o >> 14) & 7u;
  unsigned int tap = o >> 17;
  unsigned int co = cb * 128u + col, ci = cic * 32u + kg * 8u + j;
  float x = w3[((size_t)co * 256u + ci) * 27u + tap];
  unsigned int p = splitpack(x);
  whi[o] = (unsigned short)(p & 0xffffu);
  wlo[o] = (unsigned short)(p >> 16);
}

// ---------------- codebook -> tiled hi/lo ----------------
__global__ void split_cb_k(const float* __restrict__ cb, unsigned short* __restrict__ cbhi,
                           unsigned short* __restrict__ cblo) {
  unsigned int o = blockIdx.x * 256u + threadIdx.x;      // grid exact: 16384*256 = 2^22
  unsigned int j   = o & 7u;
  unsigned int row = (o >> 3) & 127u;
  unsigned int kq  = (o >> 10) & 3u;
  unsigned int kc  = (o >> 12) & 15u;
  unsigned int vb  = o >> 16;
  unsigned int v = vb * 128u + row, k = kc * 32u + kq * 8u + j;
  float x = cb[(size_t)v * 512u + k];
  unsigned int p = splitpack(x);
  cbhi[o] = (unsigned short)(p & 0xffffu);
  cblo[o] = (unsigned short)(p >> 16);
}

// ---------------- codebook squared norms ----------------
__global__ void c2_k(const float* __restrict__ cb, float* __restrict__ c2) {
  const int wid = threadIdx.x >> 6, lane = threadIdx.x & 63;
  const int v = blockIdx.x * 4 + wid;
  const float* row = cb + (size_t)v * 512 + lane * 8;
  float4 a = *(const float4*)row, b = *(const float4*)(row + 4);
  float s = a.x*a.x + a.y*a.y + a.z*a.z + a.w*a.w
          + b.x*b.x + b.y*b.y + b.z*b.z + b.w*b.w;
  #pragma unroll
  for (int off = 32; off; off >>= 1) s += __shfl_down(s, off);
  if (lane == 0) c2[v] = s;
}

// ---------------- conv2: MFMA, double-buffered LDS, 1 barrier/chunk, depth-2 ----------
#define NCH2 108   // 27 taps * 4 ci-chunks of 32
#define BUFO 16384
__global__ __launch_bounds__(512) void conv2_mfma_k(
    const unsigned int* __restrict__ xp,    // h1p (j-grouped planes)
    const unsigned short* __restrict__ whi, const unsigned short* __restrict__ wlo,
    const float* __restrict__ bias,
    unsigned int* __restrict__ h2p) {
  __shared__ __align__(16) unsigned short lds[32768];   // 2 x 32 KB

  const int tid  = threadIdx.x;
  const int lane = tid & 63;
  const int wid  = tid >> 6;           // 8 waves: 2(M) x 4(N)
  const int wm   = wid >> 2, wn = wid & 3;
  const int cbk = blockIdx.x;          // 0..1 co block
  const int nb  = blockIdx.y;          // 0..7 h-strip of 4 rows
  const int bt  = blockIdx.z;          // 0..31
  const int b = bt >> 4, t = bt & 15;

  const int skg = tid >> 7;            // 0..3
  const int sn  = tid & 127;           // token
  const int s_hout = nb * 4 + (sn >> 5);
  const int s_wout = sn & 31;

  const int lc = lane & 15, kgl = lane >> 4;

  f32x4 acc[4][2];
  #pragma unroll
  for (int mf = 0; mf < 4; ++mf)
    #pragma unroll
    for (int nf = 0; nf < 2; ++nf) acc[mf][nf] = (f32x4)(0.f);

  auto issue = [&](int ic, uint4& xa, uint4& xb, uint4& wh, uint4& wl) {
    const int tap = ic >> 2, cic = ic & 3;
    const int kd = tap / 9, r9 = tap % 9;
    const int kh = r9 / 3, kw = r9 % 3;
    const int tt = t + kd - 1;
    const int pl = ((kh != 1) ? 2 : 0) + ((kw != 1) ? 1 : 0);
    const int r  = s_hout + (kh != 0) - 1;
    const int c  = s_wout + (kw != 0) - 1;
    const bool oob = (tt < 0) || (tt > 15) || (r < 0) || (c < 0);
    const int o = b * 8388608 + (cic * 4 + skg) * 524288 + tt * 32768 + pl * 8192 + (r * 32 + c) * 8;
    const unsigned int* src = xp + (oob ? 0 : o);
    uint4 a = *(const uint4*)src, bb = *(const uint4*)(src + 4);
    if (oob) { a = make_uint4(0u,0u,0u,0u); bb = make_uint4(0u,0u,0u,0u); }
    xa = a; xb = bb;
    const size_t slab = ((size_t)((tap * 4 + cic) * 2 + cbk)) << 12;
    wh = *(const uint4*)(whi + slab + tid * 8);
    wl = *(const uint4*)(wlo + slab + tid * 8);
  };

  auto stage = [&](int bo, const uint4& xa, const uint4& xb, const uint4& wh, const uint4& wl) {
    *(uint4*)&lds[bo + tid * 8] = wh;
    *(uint4*)&lds[bo + 4096 + tid * 8] = wl;
    uint4 H, L;
    H.x = (xa.x & 0xffffu) | (xa.y << 16);  L.x = (xa.x >> 16) | (xa.y & 0xffff0000u);
    H.y = (xa.z & 0xffffu) | (xa.w << 16);  L.y = (xa.z >> 16) | (xa.w & 0xffff0000u);
    H.z = (xb.x & 0xffffu) | (xb.y << 16);  L.z = (xb.x >> 16) | (xb.y & 0xffff0000u);
    H.w = (xb.z & 0xffffu) | (xb.w << 16);  L.w = (xb.z >> 16) | (xb.w & 0xffff0000u);
    *(uint4*)&lds[bo + 8192  + (skg * 128 + sn) * 8] = H;
    *(uint4*)&lds[bo + 12288 + (skg * 128 + sn) * 8] = L;
  };

  auto mma = [&](int bo) {
    uint4 ah[4], al[4], bh[2], bl[2];
    #pragma unroll
    for (int mf = 0; mf < 4; ++mf) {
      const int o = bo + kgl * 1024 + (wm * 64 + mf * 16 + lc) * 8;
      ah[mf] = *(const uint4*)&lds[o];
      al[mf] = *(const uint4*)&lds[o + 4096];
    }
    #pragma unroll
    for (int nf = 0; nf < 2; ++nf) {
      const int o = bo + 8192 + kgl * 1024 + (wn * 32 + nf * 16 + lc) * 8;
      bh[nf] = *(const uint4*)&lds[o];
      bl[nf] = *(const uint4*)&lds[o + 4096];
    }
    #pragma unroll
    for (int mf = 0; mf < 4; ++mf)
      #pragma unroll
      for (int nf = 0; nf < 2; ++nf) mfma_bf16(acc[mf][nf], ah[mf], bh[nf]);
    #pragma unroll
    for (int mf = 0; mf < 4; ++mf)
      #pragma unroll
      for (int nf = 0; nf < 2; ++nf) mfma_bf16(acc[mf][nf], ah[mf], bl[nf]);
    #pragma unroll
    for (int mf = 0; mf < 4; ++mf)
      #pragma unroll
      for (int nf = 0; nf < 2; ++nf) mfma_bf16(acc[mf][nf], al[mf], bh[nf]);
  };

  uint4 xa0, xb0, wh0, wl0, xa1, xb1, wh1, wl1;
  issue(0, xa0, xb0, wh0, wl0);
  issue(1, xa1, xb1, wh1, wl1);

  #pragma unroll 1
  for (int ic = 0; ic < NCH2; ic += 2) {
    stage(0, xa0, xb0, wh0, wl0);
    __syncthreads();
    if (ic + 2 < NCH2) issue(ic + 2, xa0, xb0, wh0, wl0);
    mma(0);
    stage(BUFO, xa1, xb1, wh1, wl1);
    __syncthreads();
    if (ic + 3 < NCH2) issue(ic + 3, xa1, xb1, wh1, wl1);
    mma(BUFO);
  }

  // epilogue: bias + ReLU + splitpack, scatter into j-grouped h2p planes
  const int lr4 = (lane >> 4) * 4;
  #pragma unroll
  for (int mf = 0; mf < 4; ++mf) {
    const int co0g = cbk * 128 + wm * 64 + mf * 16 + lr4;
    const float4 bv = *(const float4*)(bias + co0g);
    const float* bp = (const float*)&bv;
    const size_t gbase = (size_t)(b * 32 + (co0g >> 3)) * 131072 + (size_t)t * 8192 + (co0g & 7);
    #pragma unroll
    for (int nf = 0; nf < 2; ++nf) {
      const int n_l = wn * 32 + nf * 16 + lc;
      const int h_out = nb * 4 + (n_l >> 5);
      const int w_out = n_l & 31;
      const int pl_o = ((h_out & 1) << 1) | (w_out & 1);
      const size_t sp = gbase + (size_t)pl_o * 2048 + (size_t)((h_out >> 1) * 16 + (w_out >> 1)) * 8;
      #pragma unroll
      for (int r = 0; r < 4; ++r) {
        const float x = fmaxf(acc[mf][nf][r] + bp[r], 0.f);
        h2p[sp + r] = splitpack(x);
      }
    }
  }
}

// ---------------- conv3: MFMA, double-buffered LDS, 1 barrier/chunk, depth-2 ----------
#define NCH 216   // 27 taps * 8 ci-chunks of 32
__global__ __launch_bounds__(512) void conv3_mfma_k(
    const unsigned int* __restrict__ xp,    // h2p (j-grouped planes)
    const unsigned short* __restrict__ whi, const unsigned short* __restrict__ wlo,
    const float* __restrict__ bias,
    unsigned short* __restrict__ fhi, unsigned short* __restrict__ flo) {
  __shared__ __align__(16) unsigned short lds[32768];   // 2 x 32 KB

  const int tid  = threadIdx.x;
  const int lane = tid & 63;
  const int wid  = tid >> 6;
  const int wm   = wid >> 2, wn = wid & 3;
  const int cb = blockIdx.x;           // co block (128)
  const int hb = blockIdx.y;           // h half (8 rows)
  const int bt = blockIdx.z;
  const int b = bt >> 4, t = bt & 15;

  const int skg = tid >> 7;
  const int sn  = tid & 127;
  const int shn = hb * 8 + (sn >> 4);
  const int swn = sn & 15;

  const int lc = lane & 15, kgl = lane >> 4;

  f32x4 acc[4][2];
  #pragma unroll
  for (int mf = 0; mf < 4; ++mf)
    #pragma unroll
    for (int nf = 0; nf < 2; ++nf) acc[mf][nf] = (f32x4)(0.f);

  auto issue = [&](int ic, uint4& xa, uint4& xb, uint4& wh, uint4& wl) {
    const int tap = ic >> 3, cic = ic & 7;
    const int kd = tap / 9, r9 = tap % 9;
    const int kh = r9 / 3, kw = r9 % 3;
    const int tt = t + kd - 1;
    const int pl = ((kh != 1) ? 2 : 0) + ((kw != 1) ? 1 : 0);
    const int r  = shn + (kh != 0) - 1;
    const int c  = swn + (kw != 0) - 1;
    const bool oob = (tt < 0) || (tt > 15) || (r < 0) || (c < 0);
    const int o = b * 4194304 + (cic * 4 + skg) * 131072 + tt * 8192 + pl * 2048 + (r * 16 + c) * 8;
    const unsigned int* src = xp + (oob ? 0 : o);
    uint4 a = *(const uint4*)src, bb = *(const uint4*)(src + 4);
    if (oob) { a = make_uint4(0u,0u,0u,0u); bb = make_uint4(0u,0u,0u,0u); }
    xa = a; xb = bb;
    const size_t slab = ((size_t)((tap * 8 + cic) * 4 + cb)) << 12;
    wh = *(const uint4*)(whi + slab + tid * 8);
    wl = *(const uint4*)(wlo + slab + tid * 8);
  };

  auto stage = [&](int bo, const uint4& xa, const uint4& xb, const uint4& wh, const uint4& wl) {
    *(uint4*)&lds[bo + tid * 8] = wh;
    *(uint4*)&lds[bo + 4096 + tid * 8] = wl;
    uint4 H, L;
    H.x = (xa.x & 0xffffu) | (xa.y << 16);  L.x = (xa.x >> 16) | (xa.y & 0xffff0000u);
    H.y = (xa.z & 0xffffu) | (xa.w << 16);  L.y = (xa.z >> 16) | (xa.w & 0xffff0000u);
    H.z = (xb.x & 0xffffu) | (xb.y << 16);  L.z = (xb.x >> 16) | (xb.y & 0xffff0000u);
    H.w = (xb.z & 0xffffu) | (xb.w << 16);  L.w = (xb.z >> 16) | (xb.w & 0xffff0000u);
    *(uint4*)&lds[bo + 8192  + (skg * 128 + sn) * 8] = H;
    *(uint4*)&lds[bo + 12288 + (skg * 128 + sn) * 8] = L;
  };

  auto mma = [&](int bo) {
    uint4 ah[4], al[4], bh[2], bl[2];
    #pragma unroll
    for (int mf = 0; mf < 4; ++mf) {
      const int o = bo + kgl * 1024 + (wm * 64 + mf * 16 + lc) * 8;
      ah[mf] = *(const uint4*)&lds[o];
      al[mf] = *(const uint4*)&lds[o + 4096];
    }
    #pragma unroll
    for (int nf = 0; nf < 2; ++nf) {
      const int o = bo + 8192 + kgl * 1024 + (wn * 32 + nf * 16 + lc) * 8;
      bh[nf] = *(const uint4*)&lds[o];
      bl[nf] = *(const uint4*)&lds[o + 4096];
    }
    #pragma unroll
    for (int mf = 0; mf < 4; ++mf)
      #pragma unroll
      for (int nf = 0; nf < 2; ++nf) mfma_bf16(acc[mf][nf], ah[mf], bh[nf]);
    #pragma unroll
    for (int mf = 0; mf < 4; ++mf)
      #pragma unroll
      for (int nf = 0; nf < 2; ++nf) mfma_bf16(acc[mf][nf], ah[mf], bl[nf]);
    #pragma unroll
    for (int mf = 0; mf < 4; ++mf)
      #pragma unroll
      for (int nf = 0; nf < 2; ++nf) mfma_bf16(acc[mf][nf], al[mf], bh[nf]);
  };

  uint4 xa0, xb0, wh0, wl0, xa1, xb1, wh1, wl1;
  issue(0, xa0, xb0, wh0, wl0);
  issue(1, xa1, xb1, wh1, wl1);

  #pragma unroll 1
  for (int ic = 0; ic < NCH; ic += 2) {
    stage(0, xa0, xb0, wh0, wl0);
    __syncthreads();
    if (ic + 2 < NCH) issue(ic + 2, xa0, xb0, wh0, wl0);
    mma(0);
    stage(BUFO, xa1, xb1, wh1, wl1);
    __syncthreads();
    if (ic + 3 < NCH) issue(ic + 3, xa1, xb1, wh1, wl1);
    mma(BUFO);
  }

  // epilogue: bias add, bf16x2 split, store into tiled feature layout
  const int lr4 = (lane >> 4) * 4;
  const int tokb = b * 32 + t * 2 + hb;
  #pragma unroll
  for (int mf = 0; mf < 4; ++mf) {
    const int co0g = cb * 128 + wm * 64 + mf * 16 + lr4;
    const float4 bv = *(const float4*)(bias + co0g);
    const int kc = co0g >> 5, kq = (co0g >> 3) & 3, j0 = co0g & 7;
    #pragma unroll
    for (int nf = 0; nf < 2; ++nf) {
      const int n_l = wn * 32 + nf * 16 + lc;
      const size_t off = (size_t)(tokb * 16 + kc) * 4096 + kq * 1024 + n_l * 8 + j0;
      unsigned int p0 = splitpack(acc[mf][nf][0] + bv.x);
      unsigned int p1 = splitpack(acc[mf][nf][1] + bv.y);
      unsigned int p2 = splitpack(acc[mf][nf][2] + bv.z);
      unsigned int p3 = splitpack(acc[mf][nf][3] + bv.w);
      ushort4 h4, l4;
      h4.x = (unsigned short)(p0 & 0xffffu); l4.x = (unsigned short)(p0 >> 16);
      h4.y = (unsigned short)(p1 & 0xffffu); l4.y = (unsigned short)(p1 >> 16);
      h4.z = (unsigned short)(p2 & 0xffffu); l4.z = (unsigned short)(p2 >> 16);
      h4.w = (unsigned short)(p3 & 0xffffu); l4.w = (unsigned short)(p3 >> 16);
      *(ushort4*)(fhi + off) = h4;
      *(ushort4*)(flo + off) = l4;
    }
  }
}

// ---------------- VQ as MFMA GEMM (bf16x2) + fused argmin (unchanged) ----------------
__global__ __launch_bounds__(512) void vq_mfma_k(
    const unsigned short* __restrict__ fhi, const unsigned short* __restrict__ flo,
    const unsigned short* __restrict__ cbhi, const unsigned short* __restrict__ cblo,
    const float* __restrict__ c2,
    float* __restrict__ pval, int* __restrict__ pidx) {
  __shared__ __align__(16) unsigned short lds[16384];

  const int tid  = threadIdx.x;
  const int lane = tid & 63;
  const int wid  = tid >> 6;
  const int wm   = wid >> 2, wn = wid & 3;
  const int vb = blockIdx.x;
  const int tb = blockIdx.y;
  const int v0 = vb * 128, tok0 = tb * 128;

  const int lc = lane & 15, kgl = lane >> 4;
  const uint4* pAhi[4]; const uint4* pAlo[4];
  #pragma unroll
  for (int mf = 0; mf < 4; ++mf) {
    const int off = kgl * 1024 + (wm * 64 + mf * 16 + lc) * 8;
    pAhi[mf] = (const uint4*)&lds[off];
    pAlo[mf] = (const uint4*)&lds[4096 + off];
  }
  const uint4* pBhi[2]; const uint4* pBlo[2];
  #pragma unroll
  for (int nf = 0; nf < 2; ++nf) {
    const int off = kgl * 1024 + (wn * 32 + nf * 16 + lc) * 8;
    pBhi[nf] = (const uint4*)&lds[8192 + off];
    pBlo[nf] = (const uint4*)&lds[12288 + off];
  }
  uint4* wAhi = (uint4*)&lds[tid * 8];
  uint4* wAlo = (uint4*)&lds[4096 + tid * 8];
  uint4* wBhi = (uint4*)&lds[8192 + tid * 8];
  uint4* wBlo = (uint4*)&lds[12288 + tid * 8];

  f32x4 acc[4][2];
  #pragma unroll
  for (int mf = 0; mf < 4; ++mf)
    #pragma unroll
    for (int nf = 0; nf < 2; ++nf) acc[mf][nf] = (f32x4)(0.f);

  uint4 cah, cal, fbh, fbl;
  auto issue = [&](int kc) {
    const size_t cboff = (size_t)(vb * 16 + kc) * 4096 + tid * 8;
    const size_t foff  = (size_t)(tb * 16 + kc) * 4096 + tid * 8;
    cah = *(const uint4*)(cbhi + cboff);
    cal = *(const uint4*)(cblo + cboff);
    fbh = *(const uint4*)(fhi + foff);
    fbl = *(const uint4*)(flo + foff);
  };

  issue(0);

  for (int kc = 0; kc < 16; ++kc) {
    __syncthreads();
    *wAhi = cah;
    *wAlo = cal;
    *wBhi = fbh;
    *wBlo = fbl;
    __syncthreads();
    if (kc + 1 < 16) issue(kc + 1);

    uint4 ah[4], al[4], bh[2], bl[2];
    #pragma unroll
    for (int mf = 0; mf < 4; ++mf) { ah[mf] = *pAhi[mf]; al[mf] = *pAlo[mf]; }
    #pragma unroll
    for (int nf = 0; nf < 2; ++nf) { bh[nf] = *pBhi[nf]; bl[nf] = *pBlo[nf]; }

    #pragma unroll
    for (int mf = 0; mf < 4; ++mf)
      #pragma unroll
      for (int nf = 0; nf < 2; ++nf) mfma_bf16(acc[mf][nf], ah[mf], bh[nf]);
    #pragma unroll
    for (int mf = 0; mf < 4; ++mf)
      #pragma unroll
      for (int nf = 0; nf < 2; ++nf) mfma_bf16(acc[mf][nf], ah[mf], bl[nf]);
    #pragma unroll
    for (int mf = 0; mf < 4; ++mf)
      #pragma unroll
      for (int nf = 0; nf < 2; ++nf) mfma_bf16(acc[mf][nf], al[mf], bh[nf]);
  }

  float best[2]; int bidx[2];
  best[0] = best[1] = 3.4e38f; bidx[0] = bidx[1] = 0;
  #pragma unroll
  for (int mf = 0; mf < 4; ++mf) {
    float cc[4];
    *(float4*)cc = *(const float4*)(c2 + v0 + wm * 64 + mf * 16 + kgl * 4);
    #pragma unroll
    for (int nf = 0; nf < 2; ++nf) {
      #pragma unroll
      for (int r = 0; r < 4; ++r) {
        const float d = cc[r] - 2.f * acc[mf][nf][r];
        const int vg = v0 + wm * 64 + mf * 16 + kgl * 4 + r;
        if (d < best[nf] || (d == best[nf] && vg < bidx[nf])) { best[nf] = d; bidx[nf] = vg; }
      }
    }
  }
  #pragma unroll
  for (int off = 16; off <= 32; off <<= 1) {
    #pragma unroll
    for (int nf = 0; nf < 2; ++nf) {
      const float ov = __shfl_xor(best[nf], off);
      const int   oi = __shfl_xor(bidx[nf], off);
      if (ov < best[nf] || (ov == best[nf] && oi < bidx[nf])) { best[nf] = ov; bidx[nf] = oi; }
    }
  }
  if (lane < 16) {
    #pragma unroll
    for (int nf = 0; nf < 2; ++nf) {
      const int tok = tok0 + wn * 32 + nf * 16 + lane;
      const int slot = vb * 2 + wm;
      pval[(size_t)tok * 128 + slot] = best[nf];
      pidx[(size_t)tok * 128 + slot] = bidx[nf];
    }
  }
}

__global__ void vq_reduce_k(const float* __restrict__ pval, const int* __restrict__ pidx,
                            int* __restrict__ tokens, float* __restrict__ out_tok) {
  const int tok = blockIdx.x * blockDim.x + threadIdx.x;  // 8192
  float best = 3.4e38f; int bi = 0;
  for (int s = 0; s < 128; ++s) {
    const float v = pval[(size_t)tok * 128 + s];
    const int idx = pidx[(size_t)tok * 128 + s];
    if (v < best || (v == best && idx < bi)) { best = v; bi = idx; }
  }
  tokens[tok] = bi;
  out_tok[tok] = (float)bi;
}

__global__ void gather_k(const int* __restrict__ tokens, const float* __restrict__ emb,
                         float* __restrict__ out) {
  const int i = blockIdx.x * blockDim.x + threadIdx.x;  // 1,048,576 float4s
  const int n = i >> 7;
  const int c4 = (i & 127) * 4;
  const int tk = tokens[n];
  float4 v = *(const float4*)(emb + (size_t)tk * 512 + c4);
  *(float4*)(out + (size_t)n * 512 + c4) = v;
}

extern "C" void kernel_launch(void* const* d_in, const int* in_sizes, int n_in,
                              void* d_out, int out_size, void* d_ws, size_t ws_size,
                              hipStream_t stream) {
  const float* video = (const float*)d_in[0];
  const float* w1 = (const float*)d_in[1];
  const float* b1 = (const float*)d_in[2];
  const float* w2 = (const float*)d_in[3];
  const float* b2 = (const float*)d_in[4];
  const float* w3 = (const float*)d_in[5];
  const float* b3 = (const float*)d_in[6];
  const float* cb  = (const float*)d_in[7];
  const float* emb = (const float*)d_in[8];

  // ---- workspace layout (float offsets) ----
  // h1p u32 [0 .. 16,777,216)           conv1 out planes (64 MiB); dead after conv2 ->
  //    fhi   ushort @ float [0 .. 2,097,152)
  //    flo   ushort @ float [2,097,152 .. 4,194,304)
  //    cbhi  ushort @ float [4,194,304 .. 6,291,456)
  //    cblo  ushort @ float [6,291,456 .. 8,388,608)
  //    c2    @ [8,388,608 .. 8,396,800)
  //    pval  @ [8,396,800 .. 9,445,376)
  //    pidx  @ [9,445,376 .. 10,493,952)
  //    tokens@ [10,493,952 .. 10,502,144)
  // h2p u32 [16,777,216 .. 25,165,824)  conv2 out planes (32 MiB)
  // d_out: w2 tiles, then w3 tiles (overwritten by final outputs)
  float* ws = (float*)d_ws;
  unsigned int* h1p = (unsigned int*)ws;
  unsigned short* fhi = (unsigned short*)(ws);
  unsigned short* flo = (unsigned short*)(ws + 2097152);
  unsigned short* cbhi = (unsigned short*)(ws + 4194304);
  unsigned short* cblo = (unsigned short*)(ws + 6291456);
  float* c2v  = ws + 8388608;
  float* pval = ws + 8396800;
  int*   pidx = (int*)(ws + 9445376);
  int*   tokens = (int*)(ws + 10493952);
  unsigned int* h2p = (unsigned int*)(ws + 16777216);
  unsigned short* w2hi = (unsigned short*)d_out;  //   884,736 ushorts
  unsigned short* w2lo = w2hi + 884736;
  unsigned short* w3hi = (unsigned short*)d_out;  // 3,538,944 ushorts
  unsigned short* w3lo = w3hi + 3538944;
  float* out_tok = (float*)d_out;
  float* out_emb = (float*)d_out + 8192;

  hipLaunchKernelGGL(conv1_k, dim3(4, 16, 32), dim3(16, 16), 0, stream, video, w1, b1, h1p);
  hipLaunchKernelGGL(split_w2_k, dim3(3456), dim3(256), 0, stream, w2, w2hi, w2lo);
  hipLaunchKernelGGL(conv2_mfma_k, dim3(2, 8, 32), dim3(512), 0, stream,
                     h1p, w2hi, w2lo, b2, h2p);
  // h1p dead; d_out w2 tiles dead -> w3 tiles
  hipLaunchKernelGGL(split_w3_k, dim3(13824), dim3(256), 0, stream, w3, w3hi, w3lo);
  hipLaunchKernelGGL(split_cb_k, dim3(16384), dim3(256), 0, stream, cb, cbhi, cblo);
  hipLaunchKernelGGL(c2_k, dim3(2048), dim3(256), 0, stream, cb, c2v);
  hipLaunchKernelGGL(conv3_mfma_k, dim3(4, 2, 32), dim3(512), 0, stream,
                     h2p, w3hi, w3lo, b3, fhi, flo);
  hipLaunchKernelGGL(vq_mfma_k, dim3(64, 64), dim3(512), 0, stream,
                     fhi, flo, cbhi, cblo, c2v, pval, pidx);
  hipLaunchKernelGGL(vq_reduce_k, dim3(32), dim3(256), 0, stream, pval, pidx, tokens, out_tok);
  hipLaunchKernelGGL(gather_k, dim3(4096), dim3(256), 0, stream, tokens, emb, out_emb);
}